// Round 2
// 317.285 us; speedup vs baseline: 1.1661x; 1.1661x over previous
//
#include <hip/hip_runtime.h>

#define NN 50000
#define NE 800000
#define NG 256
#define NB ((NN + 255) / 256)   // scan blocks
#define N4 (NN * 128 / 4)       // float4 count of x (1.6M)

typedef __attribute__((ext_vector_type(8))) short bf16x8;
typedef __attribute__((ext_vector_type(4))) float f32x4;

// ---------- bf16 helpers ----------
__device__ __forceinline__ unsigned short f2bf_rne(float f) {
    unsigned u = __float_as_uint(f);
    u += 0x7fffu + ((u >> 16) & 1u);   // round-to-nearest-even
    return (unsigned short)(u >> 16);
}
#define BF2F_LO(u) __uint_as_float((u) << 16)
#define BF2F_HI(u) __uint_as_float((u) & 0xffff0000u)

// ---------- merged: x->bf16 convert + degree histogram (deg pre-zeroed) ----------
__global__ void conv_hist(const float4* __restrict__ x, ushort4* __restrict__ xh,
                          const int* __restrict__ dst, int* __restrict__ deg,
                          int* __restrict__ eoff) {
    int i = blockIdx.x * 256 + threadIdx.x;
    if (i < N4) {
        float4 v = x[i];
        ushort4 o;
        o.x = f2bf_rne(v.x); o.y = f2bf_rne(v.y);
        o.z = f2bf_rne(v.z); o.w = f2bf_rne(v.w);
        xh[i] = o;
    }
    if (i < NE) eoff[i] = atomicAdd(&deg[dst[i]], 1);
}

// ---------- CSR scan (+ weight transpose/convert for MFMA gemm_L0) ----------
__global__ void block_scan(const int* __restrict__ deg, int* __restrict__ iscan,
                           int* __restrict__ bsum,
                           const float* __restrict__ W1, const float* __restrict__ W2,
                           const float* __restrict__ W3,
                           unsigned short* __restrict__ W1t,
                           unsigned short* __restrict__ W2t,
                           unsigned short* __restrict__ W3t) {
    // weight prep: Wt[n][k] = bf16(W[k][n]) (independent side-work, 196*256 threads)
    int gidx = blockIdx.x * 256 + threadIdx.x;
    if (gidx < 16384) {
        int n = gidx >> 7, k = gidx & 127;
        W1t[gidx] = f2bf_rne(W1[k * 128 + n]);
        W2t[gidx] = f2bf_rne(W2[k * 128 + n]);
    } else if (gidx < 24576) {
        int i2 = gidx - 16384;
        int n = i2 >> 7, k = i2 & 127;      // n in [0,64), k in [0,128)
        W3t[i2] = f2bf_rne(W3[k * 64 + n]);
    }

    __shared__ int sh[256];
    int t = threadIdx.x;
    int i = blockIdx.x * 256 + t;
    int v = (i < NN) ? deg[i] : 0;
    sh[t] = v;
    __syncthreads();
    #pragma unroll
    for (int off = 1; off < 256; off <<= 1) {
        int add = (t >= off) ? sh[t - off] : 0;
        __syncthreads();
        sh[t] += add;
        __syncthreads();
    }
    if (i < NN) iscan[i] = sh[t];
    if (t == 255) bsum[blockIdx.x] = sh[255];
}

__global__ void scan_bsum(const int* __restrict__ bsum, int* __restrict__ boff) {
    __shared__ int sh[256];
    int t = threadIdx.x;
    int v = (t < NB) ? bsum[t] : 0;
    sh[t] = v;
    __syncthreads();
    #pragma unroll
    for (int off = 1; off < 256; off <<= 1) {
        int add = (t >= off) ? sh[t - off] : 0;
        __syncthreads();
        sh[t] += add;
        __syncthreads();
    }
    if (t < NB) boff[t] = sh[t] - v;  // exclusive
}

// merged: rowptr finalize + graph-bounds (batch is sorted)
__global__ void finalize_bounds(const int* __restrict__ deg, const int* __restrict__ iscan,
                                const int* __restrict__ boff, int* __restrict__ rowptr,
                                const int* __restrict__ batch, int* __restrict__ gstart) {
    int i = blockIdx.x * 256 + threadIdx.x;
    if (i < NN) {
        rowptr[i] = iscan[i] - deg[i] + boff[blockIdx.x];
        int b = batch[i];
        if (i == 0) {
            for (int g = 0; g <= b; g++) gstart[g] = 0;
        } else {
            int p = batch[i - 1];
            for (int g = p + 1; g <= b; g++) gstart[g] = i;
        }
        if (i == NN - 1) {
            for (int g = b + 1; g <= NG; g++) gstart[g] = NN;
        }
    }
    if (i == 0) rowptr[NN] = NE;
}

__global__ void fill_csr2(const int* __restrict__ src, const int* __restrict__ dst,
                          const int* __restrict__ rowptr, const int* __restrict__ eoff,
                          int* __restrict__ esrc) {
    int e = blockIdx.x * blockDim.x + threadIdx.x;
    if (e >= NE) return;
    esrc[rowptr[dst[e]] + eoff[e]] = src[e];
}

// ---------- generic bf16 wave-cooperative gather (R11-proven) ----------
template <int C4>
__device__ __forceinline__ void gather_bf16(const uint4* __restrict__ x4,
                                            const int* __restrict__ esrc,
                                            int beg, int cnt, int node, int lane,
                                            float* a /* [8] */) {
    constexpr int EPI = 64 / C4;
    const int chunk = lane & (C4 - 1);
    const int esl   = lane / C4;
    #define ACC_U4(u) do { \
        a[0] += BF2F_LO((u).x); a[1] += BF2F_HI((u).x); \
        a[2] += BF2F_LO((u).y); a[3] += BF2F_HI((u).y); \
        a[4] += BF2F_LO((u).z); a[5] += BF2F_HI((u).z); \
        a[6] += BF2F_LO((u).w); a[7] += BF2F_HI((u).w); } while (0)
    if (esl == 0) { uint4 u = x4[(size_t)node * C4 + chunk]; ACC_U4(u); }
    for (int c = 0; c < cnt; c += 64) {
        int take = min(64, cnt - c);
        int myi = (lane < take) ? esrc[beg + c + lane] : 0;
        int i = 0;
        for (; i + 4 * EPI <= take; i += 4 * EPI) {
            int s0 = __shfl(myi, i + esl);
            int s1 = __shfl(myi, i + EPI + esl);
            int s2 = __shfl(myi, i + 2 * EPI + esl);
            int s3 = __shfl(myi, i + 3 * EPI + esl);
            uint4 u0 = x4[(size_t)s0 * C4 + chunk];
            uint4 u1 = x4[(size_t)s1 * C4 + chunk];
            uint4 u2 = x4[(size_t)s2 * C4 + chunk];
            uint4 u3 = x4[(size_t)s3 * C4 + chunk];
            ACC_U4(u0); ACC_U4(u1); ACC_U4(u2); ACC_U4(u3);
        }
        for (; i + EPI <= take; i += EPI) {
            int s = __shfl(myi, i + esl);
            uint4 u = x4[(size_t)s * C4 + chunk];
            ACC_U4(u);
        }
        int rem = take - i;
        if (rem > 0) {
            int s = __shfl(myi, i + ((esl < rem) ? esl : 0));
            uint4 u = x4[(size_t)s * C4 + chunk];
            if (esl < rem) ACC_U4(u);
        }
    }
    #undef ACC_U4
    for (int off = 32; off >= C4; off >>= 1) {
        #pragma unroll
        for (int q = 0; q < 8; q++)
            a[q] += __shfl_xor(a[q], off);
    }
}

// ---------- standalone L0 gather: one wave per node -> bf16 agg ----------
__global__ __launch_bounds__(256) void gather_L0(
        const unsigned short* __restrict__ xh, const int* __restrict__ esrc,
        const int* __restrict__ rowptr, unsigned short* __restrict__ aggh /* N x 128 bf16 */) {
    const int wave = threadIdx.x >> 6, lane = threadIdx.x & 63;
    const int node = blockIdx.x * 4 + wave;
    if (node >= NN) return;
    float a[8] = {0, 0, 0, 0, 0, 0, 0, 0};
    int beg = rowptr[node], end = rowptr[node + 1];
    gather_bf16<16>((const uint4*)xh, esrc, beg, end - beg, node, lane, a);
    if (lane < 16) {
        uint4 o;
        o.x = (unsigned)f2bf_rne(a[0]) | ((unsigned)f2bf_rne(a[1]) << 16);
        o.y = (unsigned)f2bf_rne(a[2]) | ((unsigned)f2bf_rne(a[3]) << 16);
        o.z = (unsigned)f2bf_rne(a[4]) | ((unsigned)f2bf_rne(a[5]) << 16);
        o.w = (unsigned)f2bf_rne(a[6]) | ((unsigned)f2bf_rne(a[7]) << 16);
        *(uint4*)&aggh[(size_t)node * 128 + lane * 8] = o;
    }
}

// ---------- L0 GEMM chain via MFMA bf16 (MT=64, 4 waves) ----------
// GEMM1: relu(agg@W1+b1) -> GEMM2: BN(.@W2+b2), relu -> GEMM3: .@W1_1 -> z1h
// MFMA 16x16x32 bf16 layouts: A[m=l&15][k=(l>>4)*8+j], B[k=(l>>4)*8+j][n=l&15],
// D[row=(l>>4)*4+r][col=l&15]  (m89-verified C/D mapping)
__global__ __launch_bounds__(256) void gemm_L0(
        const unsigned short* __restrict__ aggh, unsigned short* __restrict__ z1h,
        const unsigned short* __restrict__ W1t,  // [128n][128k] bf16
        const unsigned short* __restrict__ W2t,  // [128n][128k] bf16
        const unsigned short* __restrict__ W3t,  // [64n][128k] bf16
        const float* __restrict__ b1, const float* __restrict__ b2,
        const float* __restrict__ gamma, const float* __restrict__ beta,
        const float* __restrict__ mean, const float* __restrict__ var) {
    constexpr int MT = 64, LDA = 136;   // bf16 units; 272B row stride -> uniform bank-quad spread
    __shared__ __align__(16) unsigned short shA[MT * LDA];
    __shared__ __align__(16) unsigned short shB[MT * LDA];
    const int tid = threadIdx.x;
    const int wave = tid >> 6, lane = tid & 63;
    const int nodeBase = blockIdx.x * MT;
    const int lr = lane & 15;       // row (A) / col (B,D) within tile
    const int lg = lane >> 4;       // k-group (A,B) / row-group (D)
    const int lk = lg * 8;
    const int n0 = wave * 32;       // this wave's output-column base (GEMM1/2)

    // ---- stage bf16 agg tile -> shA, coalesced 16B ----
    #pragma unroll
    for (int j = 0; j < 4; j++) {
        int f = tid + j * 256;              // uint4 index within tile (1024 total)
        int row = f >> 4, c = f & 15;
        int node = nodeBase + row;
        uint4 v = (node < NN) ? ((const uint4*)aggh)[(size_t)node * 16 + c]
                              : make_uint4(0u, 0u, 0u, 0u);
        *(uint4*)&shA[row * LDA + c * 8] = v;
    }
    __syncthreads();

    f32x4 acc[4][2];

    // ---- GEMM1: h1 = relu(A @ W1 + b1); wave owns cols [n0, n0+32) ----
    {
        float bv0 = b1[n0 + lr], bv1 = b1[n0 + 16 + lr];
        #pragma unroll
        for (int m = 0; m < 4; m++) {
            f32x4 c0 = {bv0, bv0, bv0, bv0};
            f32x4 c1 = {bv1, bv1, bv1, bv1};
            acc[m][0] = c0; acc[m][1] = c1;
        }
        #pragma unroll
        for (int ks = 0; ks < 4; ks++) {
            const int k0 = ks * 32 + lk;
            bf16x8 wb0 = *(const bf16x8*)&W1t[(n0 + lr) * 128 + k0];
            bf16x8 wb1 = *(const bf16x8*)&W1t[(n0 + 16 + lr) * 128 + k0];
            #pragma unroll
            for (int m = 0; m < 4; m++) {
                bf16x8 af = *(const bf16x8*)&shA[(m * 16 + lr) * LDA + k0];
                acc[m][0] = __builtin_amdgcn_mfma_f32_16x16x32_bf16(af, wb0, acc[m][0], 0, 0, 0);
                acc[m][1] = __builtin_amdgcn_mfma_f32_16x16x32_bf16(af, wb1, acc[m][1], 0, 0, 0);
            }
        }
    }
    // relu -> bf16 -> shB (A-layout for GEMM2)
    #pragma unroll
    for (int m = 0; m < 4; m++) {
        #pragma unroll
        for (int nt = 0; nt < 2; nt++) {
            #pragma unroll
            for (int r = 0; r < 4; r++) {
                shB[(m * 16 + lg * 4 + r) * LDA + (n0 + nt * 16 + lr)] =
                    f2bf_rne(fmaxf(acc[m][nt][r], 0.f));
            }
        }
    }
    __syncthreads();

    // ---- GEMM2: h2 = relu(BN(h1 @ W2 + b2)) ----
    {
        float bv0 = b2[n0 + lr], bv1 = b2[n0 + 16 + lr];
        #pragma unroll
        for (int m = 0; m < 4; m++) {
            f32x4 c0 = {bv0, bv0, bv0, bv0};
            f32x4 c1 = {bv1, bv1, bv1, bv1};
            acc[m][0] = c0; acc[m][1] = c1;
        }
        #pragma unroll
        for (int ks = 0; ks < 4; ks++) {
            const int k0 = ks * 32 + lk;
            bf16x8 wb0 = *(const bf16x8*)&W2t[(n0 + lr) * 128 + k0];
            bf16x8 wb1 = *(const bf16x8*)&W2t[(n0 + 16 + lr) * 128 + k0];
            #pragma unroll
            for (int m = 0; m < 4; m++) {
                bf16x8 af = *(const bf16x8*)&shB[(m * 16 + lr) * LDA + k0];
                acc[m][0] = __builtin_amdgcn_mfma_f32_16x16x32_bf16(af, wb0, acc[m][0], 0, 0, 0);
                acc[m][1] = __builtin_amdgcn_mfma_f32_16x16x32_bf16(af, wb1, acc[m][1], 0, 0, 0);
            }
        }
    }
    float s0 = gamma[n0 + lr]      * (1.0f / sqrtf(var[n0 + lr] + 1e-5f));
    float t0 = beta[n0 + lr]       - mean[n0 + lr] * s0;
    float s1 = gamma[n0 + 16 + lr] * (1.0f / sqrtf(var[n0 + 16 + lr] + 1e-5f));
    float t1 = beta[n0 + 16 + lr]  - mean[n0 + 16 + lr] * s1;
    #pragma unroll
    for (int m = 0; m < 4; m++) {
        #pragma unroll
        for (int nt = 0; nt < 2; nt++) {
            float sc = nt ? s1 : s0, sf = nt ? t1 : t0;
            #pragma unroll
            for (int r = 0; r < 4; r++) {
                float y = fmaxf(fmaf(acc[m][nt][r], sc, sf), 0.f);
                shA[(m * 16 + lg * 4 + r) * LDA + (n0 + nt * 16 + lr)] = f2bf_rne(y);
            }
        }
    }
    __syncthreads();

    // ---- GEMM3: z1 = h2 @ W1_1 (no bias/act); wave owns cols [wave*16, +16) ----
    f32x4 a3[4];
    #pragma unroll
    for (int m = 0; m < 4; m++) {
        f32x4 z = {0.f, 0.f, 0.f, 0.f};
        a3[m] = z;
    }
    #pragma unroll
    for (int ks = 0; ks < 4; ks++) {
        const int k0 = ks * 32 + lk;
        bf16x8 wb = *(const bf16x8*)&W3t[(wave * 16 + lr) * 128 + k0];
        #pragma unroll
        for (int m = 0; m < 4; m++) {
            bf16x8 af = *(const bf16x8*)&shA[(m * 16 + lr) * LDA + k0];
            a3[m] = __builtin_amdgcn_mfma_f32_16x16x32_bf16(af, wb, a3[m], 0, 0, 0);
        }
    }
    #pragma unroll
    for (int m = 0; m < 4; m++) {
        #pragma unroll
        for (int r = 0; r < 4; r++) {
            int node = nodeBase + m * 16 + lg * 4 + r;
            if (node < NN)
                z1h[(size_t)node * 64 + wave * 16 + lr] = f2bf_rne(a3[m][r]);
        }
    }
}

// ---------- fused layer 1 (MT=32, R11-proven): bf16 gather z1(64) -> +b1,relu -> W2_1+BN+relu -> xW1_2 -> z2h ----------
__global__ __launch_bounds__(256) void fused_L1(
        const unsigned short* __restrict__ z1h, const int* __restrict__ esrc,
        const int* __restrict__ rowptr, unsigned short* __restrict__ z2h,
        const float* __restrict__ b1, const float* __restrict__ W2,
        const float* __restrict__ b2, const float* __restrict__ gamma,
        const float* __restrict__ beta, const float* __restrict__ mean,
        const float* __restrict__ var, const float* __restrict__ Wn /* W1_2: 64x32 */) {
    constexpr int MT = 32, LD = 68;
    __shared__ float sh[MT * LD];
    const int tid = threadIdx.x, wave = tid >> 6, lane = tid & 63;
    const int nodeBase = blockIdx.x * MT;

    for (int r = wave; r < MT; r += 4) {
        int node = nodeBase + r;
        float a[8] = {0, 0, 0, 0, 0, 0, 0, 0};
        if (node < NN) {
            int beg = rowptr[node], end = rowptr[node + 1];
            gather_bf16<8>((const uint4*)z1h, esrc, beg, end - beg, node, lane, a);
        }
        if (lane < 8) {
            float4 b0 = *(const float4*)&b1[lane * 8];
            float4 b4 = *(const float4*)&b1[lane * 8 + 4];
            *(float4*)&sh[r * LD + lane * 8] = make_float4(
                fmaxf(a[0] + b0.x, 0.f), fmaxf(a[1] + b0.y, 0.f),
                fmaxf(a[2] + b0.z, 0.f), fmaxf(a[3] + b0.w, 0.f));
            *(float4*)&sh[r * LD + lane * 8 + 4] = make_float4(
                fmaxf(a[4] + b4.x, 0.f), fmaxf(a[5] + b4.y, 0.f),
                fmaxf(a[6] + b4.z, 0.f), fmaxf(a[7] + b4.w, 0.f));
        }
    }
    __syncthreads();

    // GEMM_A: 64->64 (W2_1) + BN + relu. CT=16, RT=16, RPT=2
    const int colid = tid % 16, rowid = tid / 16;
    const int c0 = colid * 4, r0 = rowid * 2;
    float acc[2][4];
    {
        float4 bv = *(const float4*)&b2[c0];
        #pragma unroll
        for (int i = 0; i < 2; i++) {
            acc[i][0] = bv.x; acc[i][1] = bv.y; acc[i][2] = bv.z; acc[i][3] = bv.w;
        }
        #pragma unroll 2
        for (int k4 = 0; k4 < 16; k4++) {
            float4 w[4];
            #pragma unroll
            for (int kk = 0; kk < 4; kk++)
                w[kk] = *(const float4*)&W2[(k4 * 4 + kk) * 64 + c0];
            #pragma unroll
            for (int i = 0; i < 2; i++) {
                float4 a = *(const float4*)&sh[(r0 + i) * LD + k4 * 4];
                const float av[4] = {a.x, a.y, a.z, a.w};
                #pragma unroll
                for (int kk = 0; kk < 4; kk++) {
                    const float* wp = (const float*)&w[kk];
                    #pragma unroll
                    for (int j = 0; j < 4; j++)
                        acc[i][j] = fmaf(av[kk], wp[j], acc[i][j]);
                }
            }
        }
    }
    float4 gv = *(const float4*)&gamma[c0];
    float4 bev = *(const float4*)&beta[c0];
    float4 mv = *(const float4*)&mean[c0];
    float4 vv = *(const float4*)&var[c0];
    float scale[4], shift[4];
    {
        const float* gp = (const float*)&gv; const float* bp = (const float*)&bev;
        const float* mp = (const float*)&mv; const float* vp = (const float*)&vv;
        #pragma unroll
        for (int j = 0; j < 4; j++) {
            scale[j] = gp[j] * (1.0f / sqrtf(vp[j] + 1e-5f));
            shift[j] = bp[j] - mp[j] * scale[j];
        }
    }
    __syncthreads();
    #pragma unroll
    for (int i = 0; i < 2; i++) {
        float4 y;
        y.x = fmaxf(fmaf(acc[i][0], scale[0], shift[0]), 0.f);
        y.y = fmaxf(fmaf(acc[i][1], scale[1], shift[1]), 0.f);
        y.z = fmaxf(fmaf(acc[i][2], scale[2], shift[2]), 0.f);
        y.w = fmaxf(fmaf(acc[i][3], scale[3], shift[3]), 0.f);
        *(float4*)&sh[(r0 + i) * LD + c0] = y;
    }
    __syncthreads();

    // GEMM_B: y(64) @ W1_2(64x32) -> z2 (bf16). CT=8, RT=32, RPT=1
    {
        const int colid2 = tid % 8, rowid2 = tid / 8;
        const int c0b = colid2 * 4, r0b = rowid2;
        float a3[4] = {};
        #pragma unroll 2
        for (int k4 = 0; k4 < 16; k4++) {
            float4 w[4];
            #pragma unroll
            for (int kk = 0; kk < 4; kk++)
                w[kk] = *(const float4*)&Wn[(k4 * 4 + kk) * 32 + c0b];
            float4 a = *(const float4*)&sh[r0b * LD + k4 * 4];
            const float av[4] = {a.x, a.y, a.z, a.w};
            #pragma unroll
            for (int kk = 0; kk < 4; kk++) {
                const float* wp = (const float*)&w[kk];
                #pragma unroll
                for (int j = 0; j < 4; j++)
                    a3[j] = fmaf(av[kk], wp[j], a3[j]);
            }
        }
        int node = nodeBase + r0b;
        if (node < NN) {
            ushort4 o;
            o.x = f2bf_rne(a3[0]); o.y = f2bf_rne(a3[1]);
            o.z = f2bf_rne(a3[2]); o.w = f2bf_rne(a3[3]);
            *(ushort4*)&z2h[(size_t)node * 32 + c0b] = o;
        }
    }
}

// ---------- fused layer 2 (MT=32, R11-proven): bf16 gather z2(32) -> +b1,relu -> W2_2+BN -> xW_lin -> logits ----------
__global__ __launch_bounds__(256) void fused_L2(
        const unsigned short* __restrict__ z2h, const int* __restrict__ esrc,
        const int* __restrict__ rowptr, float* __restrict__ logits,
        const float* __restrict__ b1, const float* __restrict__ W2,
        const float* __restrict__ b2, const float* __restrict__ gamma,
        const float* __restrict__ beta, const float* __restrict__ mean,
        const float* __restrict__ var, const float* __restrict__ Wl,
        const float* __restrict__ bl) {
    constexpr int MT = 32, LD = 36;
    __shared__ float sh[MT * LD];
    const int tid = threadIdx.x, wave = tid >> 6, lane = tid & 63;
    const int nodeBase = blockIdx.x * MT;

    for (int r = wave; r < MT; r += 4) {
        int node = nodeBase + r;
        float a[8] = {0, 0, 0, 0, 0, 0, 0, 0};
        if (node < NN) {
            int beg = rowptr[node], end = rowptr[node + 1];
            gather_bf16<4>((const uint4*)z2h, esrc, beg, end - beg, node, lane, a);
        }
        if (lane < 4) {
            float4 b0 = *(const float4*)&b1[lane * 8];
            float4 b4 = *(const float4*)&b1[lane * 8 + 4];
            *(float4*)&sh[r * LD + lane * 8] = make_float4(
                fmaxf(a[0] + b0.x, 0.f), fmaxf(a[1] + b0.y, 0.f),
                fmaxf(a[2] + b0.z, 0.f), fmaxf(a[3] + b0.w, 0.f));
            *(float4*)&sh[r * LD + lane * 8 + 4] = make_float4(
                fmaxf(a[4] + b4.x, 0.f), fmaxf(a[5] + b4.y, 0.f),
                fmaxf(a[6] + b4.z, 0.f), fmaxf(a[7] + b4.w, 0.f));
        }
    }
    __syncthreads();

    // GEMM: 32->32 (W2_2) + BN (no relu), dot W_lin. CT=8, RT=32, RPT=1
    const int colid = tid % 8, rowid = tid / 8;
    const int c0 = colid * 4, r0 = rowid;
    float acc[4];
    {
        float4 bv = *(const float4*)&b2[c0];
        acc[0] = bv.x; acc[1] = bv.y; acc[2] = bv.z; acc[3] = bv.w;
        #pragma unroll
        for (int k4 = 0; k4 < 8; k4++) {
            float4 w[4];
            #pragma unroll
            for (int kk = 0; kk < 4; kk++)
                w[kk] = *(const float4*)&W2[(k4 * 4 + kk) * 32 + c0];
            float4 a = *(const float4*)&sh[r0 * LD + k4 * 4];
            const float av[4] = {a.x, a.y, a.z, a.w};
            #pragma unroll
            for (int kk = 0; kk < 4; kk++) {
                const float* wp = (const float*)&w[kk];
                #pragma unroll
                for (int j = 0; j < 4; j++)
                    acc[j] = fmaf(av[kk], wp[j], acc[j]);
            }
        }
    }
    float4 gv = *(const float4*)&gamma[c0];
    float4 bev = *(const float4*)&beta[c0];
    float4 mv = *(const float4*)&mean[c0];
    float4 vv = *(const float4*)&var[c0];
    float4 wl = *(const float4*)&Wl[c0];
    float p = 0.f;
    {
        const float* gp = (const float*)&gv; const float* bp = (const float*)&bev;
        const float* mp = (const float*)&mv; const float* vp = (const float*)&vv;
        const float* wp = (const float*)&wl;
        #pragma unroll
        for (int j = 0; j < 4; j++) {
            float sc = gp[j] * (1.0f / sqrtf(vp[j] + 1e-5f));
            float y = (acc[j] - mp[j]) * sc + bp[j];
            p = fmaf(y, wp[j], p);
        }
    }
    p += __shfl_xor(p, 1);
    p += __shfl_xor(p, 2);
    p += __shfl_xor(p, 4);
    int node = nodeBase + r0;
    if ((tid & 7) == 0 && node < NN)
        logits[node] = (p + bl[0]) * 0.2f;
}

// ---------- head ----------
__global__ __launch_bounds__(256) void seg_softmax(
        const float* __restrict__ logits, const int* __restrict__ gstart,
        float* __restrict__ out) {
    __shared__ float slog[1024];
    __shared__ float sred[4];
    __shared__ float sbc[2];
    int g = blockIdx.x;
    int beg = gstart[g], end = gstart[g + 1];
    int cnt = end - beg;
    int t = threadIdx.x;
    if (cnt <= 0) return;
    bool fits = (cnt <= 1024);

    float lmax = -3.402823466e+38f;
    for (int i = t; i < cnt; i += 256) {
        float lg = logits[beg + i];
        if (fits) slog[i] = lg;
        lmax = fmaxf(lmax, lg);
    }
    #pragma unroll
    for (int off = 32; off > 0; off >>= 1)
        lmax = fmaxf(lmax, __shfl_down(lmax, off));
    if ((t & 63) == 0) sred[t >> 6] = lmax;
    __syncthreads();
    if (t == 0) sbc[0] = fmaxf(fmaxf(sred[0], sred[1]), fmaxf(sred[2], sred[3]));
    __syncthreads();
    float gm = sbc[0];

    float lsum = 0.f;
    for (int i = t; i < cnt; i += 256) {
        float lg = fits ? slog[i] : logits[beg + i];
        float e = expf(lg - gm);
        if (fits) slog[i] = e;
        lsum += e;
    }
    #pragma unroll
    for (int off = 32; off > 0; off >>= 1)
        lsum += __shfl_down(lsum, off);
    __syncthreads();
    if ((t & 63) == 0) sred[t >> 6] = lsum;
    __syncthreads();
    if (t == 0) sbc[1] = (sred[0] + sred[1]) + (sred[2] + sred[3]);
    __syncthreads();
    float inv = 1.0f / sbc[1];

    for (int i = t; i < cnt; i += 256) {
        float e = fits ? slog[i] : expf(logits[beg + i] - gm);
        out[beg + i] = e * inv;
    }
}

// ---------- launch ----------
extern "C" void kernel_launch(void* const* d_in, const int* in_sizes, int n_in,
                              void* d_out, int out_size, void* d_ws, size_t ws_size,
                              hipStream_t stream) {
    const float* x    = (const float*)d_in[0];
    const int*   ei   = (const int*)d_in[1];
    const int*   srcI = ei;
    const int*   dstI = ei + NE;
    const int*   batch = (const int*)d_in[2];

    const float* P[29];
    for (int i = 0; i < 29; i++) P[i] = (const float*)d_in[i];
    const float* Wlin = P[27];
    const float* blin = P[28];

    unsigned short* xh  = (unsigned short*)d_ws;       // N x 128 bf16
    unsigned short* z1h = xh + (size_t)NN * 128;       // N x 64 bf16
    unsigned short* z2h = z1h + (size_t)NN * 64;       // N x 32 bf16
    float* logits = (float*)(z2h + (size_t)NN * 32);   // N
    int* gstart = (int*)(logits + NN);                 // NG+1
    int* deg    = gstart + NG + 1;                     // N
    int* iscan  = deg + NN;                            // N
    int* rowptr = iscan + NN;                          // N+1
    int* bsum   = rowptr + NN + 1;                     // NB
    int* boff   = bsum + NB;                           // NB
    int* eoff   = boff + NB;                           // E
    int* esrc   = eoff + NE;                           // E
    uintptr_t pal = ((uintptr_t)(esrc + NE) + 255) & ~(uintptr_t)255;
    unsigned short* aggh = (unsigned short*)pal;       // N x 128 bf16 (16B-aligned)
    unsigned short* W1t  = aggh + (size_t)NN * 128;    // 128x128 bf16 [n][k]
    unsigned short* W2t  = W1t + 16384;                // 128x128 bf16 [n][k]
    unsigned short* W3t  = W2t + 16384;                // 64x128 bf16 [n][k]
    float* outp = (float*)d_out;

    const int TB = 256;

    // ---- merged convert + CSR histogram (grid covers N4 > NE) ----
    hipMemsetAsync(deg, 0, NN * sizeof(int), stream);
    conv_hist<<<(N4 + TB - 1) / TB, TB, 0, stream>>>(
        (const float4*)x, (ushort4*)xh, dstI, deg, eoff);

    block_scan<<<NB, 256, 0, stream>>>(deg, iscan, bsum,
        P[3], P[5], P[11], W1t, W2t, W3t);
    scan_bsum<<<1, 256, 0, stream>>>(bsum, boff);
    finalize_bounds<<<NB, 256, 0, stream>>>(deg, iscan, boff, rowptr, batch, gstart);
    fill_csr2<<<(NE + TB - 1) / TB, TB, 0, stream>>>(srcI, dstI, rowptr, eoff, esrc);

    const int GB  = (NN + 3) / 4;      // gather_L0: 1 wave/node
    const int FB64 = (NN + 63) / 64;
    const int FB32 = (NN + 31) / 32;

    gather_L0<<<GB, 256, 0, stream>>>(xh, esrc, rowptr, aggh);
    gemm_L0<<<FB64, 256, 0, stream>>>(aggh, z1h, W1t, W2t, W3t,
        P[4], P[6], P[7], P[8], P[9], P[10]);
    fused_L1<<<FB32, 256, 0, stream>>>(z1h, esrc, rowptr, z2h,
        P[12], P[13], P[14], P[15], P[16], P[17], P[18], P[19]);
    fused_L2<<<FB32, 256, 0, stream>>>(z2h, esrc, rowptr, logits,
        P[20], P[21], P[22], P[23], P[24], P[25], P[26], Wlin, blin);

    seg_softmax<<<NG, 256, 0, stream>>>(logits, gstart, outp);
}

// Round 3
// 305.557 us; speedup vs baseline: 1.2108x; 1.0384x over previous
//
#include <hip/hip_runtime.h>

#define NN 50000
#define NE 800000
#define NG 256
#define NB ((NN + 255) / 256)   // scan blocks
#define N4 (NN * 128 / 4)       // float4 count of x (1.6M)

typedef __attribute__((ext_vector_type(8))) short bf16x8;
typedef __attribute__((ext_vector_type(4))) float f32x4;

// ---------- bf16 helpers ----------
__device__ __forceinline__ unsigned short f2bf_rne(float f) {
    unsigned u = __float_as_uint(f);
    u += 0x7fffu + ((u >> 16) & 1u);   // round-to-nearest-even
    return (unsigned short)(u >> 16);
}
#define BF2F_LO(u) __uint_as_float((u) << 16)
#define BF2F_HI(u) __uint_as_float((u) & 0xffff0000u)

// ---------- merged: x->bf16 convert + degree histogram (deg pre-zeroed) ----------
__global__ void conv_hist(const float4* __restrict__ x, ushort4* __restrict__ xh,
                          const int* __restrict__ dst, int* __restrict__ deg,
                          int* __restrict__ eoff) {
    int i = blockIdx.x * 256 + threadIdx.x;
    if (i < N4) {
        float4 v = x[i];
        ushort4 o;
        o.x = f2bf_rne(v.x); o.y = f2bf_rne(v.y);
        o.z = f2bf_rne(v.z); o.w = f2bf_rne(v.w);
        xh[i] = o;
    }
    if (i < NE) eoff[i] = atomicAdd(&deg[dst[i]], 1);
}

// ---------- CSR scan (+ weight transpose/convert for MFMA gemm_L0) ----------
__global__ void block_scan(const int* __restrict__ deg, int* __restrict__ iscan,
                           int* __restrict__ bsum,
                           const float* __restrict__ W1, const float* __restrict__ W2,
                           const float* __restrict__ W3,
                           unsigned short* __restrict__ W1t,
                           unsigned short* __restrict__ W2t,
                           unsigned short* __restrict__ W3t) {
    // weight prep: Wt[n][k] = bf16(W[k][n]) (independent side-work)
    int gidx = blockIdx.x * 256 + threadIdx.x;
    if (gidx < 16384) {
        int n = gidx >> 7, k = gidx & 127;
        W1t[gidx] = f2bf_rne(W1[k * 128 + n]);
        W2t[gidx] = f2bf_rne(W2[k * 128 + n]);
    } else if (gidx < 24576) {
        int i2 = gidx - 16384;
        int n = i2 >> 7, k = i2 & 127;      // n in [0,64), k in [0,128)
        W3t[i2] = f2bf_rne(W3[k * 64 + n]);
    }

    __shared__ int sh[256];
    int t = threadIdx.x;
    int i = blockIdx.x * 256 + t;
    int v = (i < NN) ? deg[i] : 0;
    sh[t] = v;
    __syncthreads();
    #pragma unroll
    for (int off = 1; off < 256; off <<= 1) {
        int add = (t >= off) ? sh[t - off] : 0;
        __syncthreads();
        sh[t] += add;
        __syncthreads();
    }
    if (i < NN) iscan[i] = sh[t];
    if (t == 255) bsum[blockIdx.x] = sh[255];
}

__global__ void scan_bsum(const int* __restrict__ bsum, int* __restrict__ boff) {
    __shared__ int sh[256];
    int t = threadIdx.x;
    int v = (t < NB) ? bsum[t] : 0;
    sh[t] = v;
    __syncthreads();
    #pragma unroll
    for (int off = 1; off < 256; off <<= 1) {
        int add = (t >= off) ? sh[t - off] : 0;
        __syncthreads();
        sh[t] += add;
        __syncthreads();
    }
    if (t < NB) boff[t] = sh[t] - v;  // exclusive
}

// merged: rowptr finalize + graph-bounds (batch is sorted)
__global__ void finalize_bounds(const int* __restrict__ deg, const int* __restrict__ iscan,
                                const int* __restrict__ boff, int* __restrict__ rowptr,
                                const int* __restrict__ batch, int* __restrict__ gstart) {
    int i = blockIdx.x * 256 + threadIdx.x;
    if (i < NN) {
        rowptr[i] = iscan[i] - deg[i] + boff[blockIdx.x];
        int b = batch[i];
        if (i == 0) {
            for (int g = 0; g <= b; g++) gstart[g] = 0;
        } else {
            int p = batch[i - 1];
            for (int g = p + 1; g <= b; g++) gstart[g] = i;
        }
        if (i == NN - 1) {
            for (int g = b + 1; g <= NG; g++) gstart[g] = NN;
        }
    }
    if (i == 0) rowptr[NN] = NE;
}

__global__ void fill_csr2(const int* __restrict__ src, const int* __restrict__ dst,
                          const int* __restrict__ rowptr, const int* __restrict__ eoff,
                          int* __restrict__ esrc) {
    int e = blockIdx.x * blockDim.x + threadIdx.x;
    if (e >= NE) return;
    esrc[rowptr[dst[e]] + eoff[e]] = src[e];
}

// ---------- bf16 wave-cooperative gathers ----------
// All variants: C lane-chunks per row, EPI = 64/C edges per pass.
// 4x / 2x / 1x unroll keeps up to 4 independent loads in flight (MLP depth).

// 16B-lane variant (rows >= 256B): used for x (128 cols)
template <int C4>
__device__ __forceinline__ void gather_bf16(const uint4* __restrict__ x4,
                                            const int* __restrict__ esrc,
                                            int beg, int cnt, int node, int lane,
                                            float* a /* [8] */) {
    constexpr int EPI = 64 / C4;
    const int chunk = lane & (C4 - 1);
    const int esl   = lane / C4;
    #define ACC_U4(u) do { \
        a[0] += BF2F_LO((u).x); a[1] += BF2F_HI((u).x); \
        a[2] += BF2F_LO((u).y); a[3] += BF2F_HI((u).y); \
        a[4] += BF2F_LO((u).z); a[5] += BF2F_HI((u).z); \
        a[6] += BF2F_LO((u).w); a[7] += BF2F_HI((u).w); } while (0)
    if (esl == 0) { uint4 u = x4[(size_t)node * C4 + chunk]; ACC_U4(u); }
    for (int c = 0; c < cnt; c += 64) {
        int take = min(64, cnt - c);
        int myi = (lane < take) ? esrc[beg + c + lane] : 0;
        int i = 0;
        for (; i + 4 * EPI <= take; i += 4 * EPI) {
            int s0 = __shfl(myi, i + esl);
            int s1 = __shfl(myi, i + EPI + esl);
            int s2 = __shfl(myi, i + 2 * EPI + esl);
            int s3 = __shfl(myi, i + 3 * EPI + esl);
            uint4 u0 = x4[(size_t)s0 * C4 + chunk];
            uint4 u1 = x4[(size_t)s1 * C4 + chunk];
            uint4 u2 = x4[(size_t)s2 * C4 + chunk];
            uint4 u3 = x4[(size_t)s3 * C4 + chunk];
            ACC_U4(u0); ACC_U4(u1); ACC_U4(u2); ACC_U4(u3);
        }
        if (i + 2 * EPI <= take) {
            int s0 = __shfl(myi, i + esl);
            int s1 = __shfl(myi, i + EPI + esl);
            uint4 u0 = x4[(size_t)s0 * C4 + chunk];
            uint4 u1 = x4[(size_t)s1 * C4 + chunk];
            ACC_U4(u0); ACC_U4(u1);
            i += 2 * EPI;
        }
        if (i + EPI <= take) {
            int s = __shfl(myi, i + esl);
            uint4 u = x4[(size_t)s * C4 + chunk];
            ACC_U4(u);
            i += EPI;
        }
        int rem = take - i;
        if (rem > 0) {
            int s = __shfl(myi, i + ((esl < rem) ? esl : 0));
            uint4 u = x4[(size_t)s * C4 + chunk];
            if (esl < rem) ACC_U4(u);
        }
    }
    #undef ACC_U4
    for (int off = 32; off >= C4; off >>= 1) {
        #pragma unroll
        for (int q = 0; q < 8; q++)
            a[q] += __shfl_xor(a[q], off);
    }
}

// 8B-lane variant (rows = 128B): used for z1 (64 cols). C=16, EPI=4.
template <int C>
__device__ __forceinline__ void gather_bf16_u2(const uint2* __restrict__ x2,
                                               const int* __restrict__ esrc,
                                               int beg, int cnt, int node, int lane,
                                               float* a /* [4] */) {
    constexpr int EPI = 64 / C;
    const int chunk = lane & (C - 1);
    const int esl   = lane / C;
    #define ACC_U2(u) do { \
        a[0] += BF2F_LO((u).x); a[1] += BF2F_HI((u).x); \
        a[2] += BF2F_LO((u).y); a[3] += BF2F_HI((u).y); } while (0)
    if (esl == 0) { uint2 u = x2[(size_t)node * C + chunk]; ACC_U2(u); }
    for (int c = 0; c < cnt; c += 64) {
        int take = min(64, cnt - c);
        int myi = (lane < take) ? esrc[beg + c + lane] : 0;
        int i = 0;
        for (; i + 4 * EPI <= take; i += 4 * EPI) {
            int s0 = __shfl(myi, i + esl);
            int s1 = __shfl(myi, i + EPI + esl);
            int s2 = __shfl(myi, i + 2 * EPI + esl);
            int s3 = __shfl(myi, i + 3 * EPI + esl);
            uint2 u0 = x2[(size_t)s0 * C + chunk];
            uint2 u1 = x2[(size_t)s1 * C + chunk];
            uint2 u2 = x2[(size_t)s2 * C + chunk];
            uint2 u3 = x2[(size_t)s3 * C + chunk];
            ACC_U2(u0); ACC_U2(u1); ACC_U2(u2); ACC_U2(u3);
        }
        if (i + 2 * EPI <= take) {
            int s0 = __shfl(myi, i + esl);
            int s1 = __shfl(myi, i + EPI + esl);
            uint2 u0 = x2[(size_t)s0 * C + chunk];
            uint2 u1 = x2[(size_t)s1 * C + chunk];
            ACC_U2(u0); ACC_U2(u1);
            i += 2 * EPI;
        }
        if (i + EPI <= take) {
            int s = __shfl(myi, i + esl);
            uint2 u = x2[(size_t)s * C + chunk];
            ACC_U2(u);
            i += EPI;
        }
        int rem = take - i;
        if (rem > 0) {
            int s = __shfl(myi, i + ((esl < rem) ? esl : 0));
            uint2 u = x2[(size_t)s * C + chunk];
            if (esl < rem) ACC_U2(u);
        }
    }
    #undef ACC_U2
    for (int off = 32; off >= C; off >>= 1) {
        #pragma unroll
        for (int q = 0; q < 4; q++)
            a[q] += __shfl_xor(a[q], off);
    }
}

// 4B-lane variant (rows = 64B): used for z2 (32 cols). C=16, EPI=4.
template <int C>
__device__ __forceinline__ void gather_bf16_u1(const unsigned* __restrict__ x1,
                                               const int* __restrict__ esrc,
                                               int beg, int cnt, int node, int lane,
                                               float* a /* [2] */) {
    constexpr int EPI = 64 / C;
    const int chunk = lane & (C - 1);
    const int esl   = lane / C;
    #define ACC_U1(u) do { \
        a[0] += BF2F_LO(u); a[1] += BF2F_HI(u); } while (0)
    if (esl == 0) { unsigned u = x1[(size_t)node * C + chunk]; ACC_U1(u); }
    for (int c = 0; c < cnt; c += 64) {
        int take = min(64, cnt - c);
        int myi = (lane < take) ? esrc[beg + c + lane] : 0;
        int i = 0;
        for (; i + 4 * EPI <= take; i += 4 * EPI) {
            int s0 = __shfl(myi, i + esl);
            int s1 = __shfl(myi, i + EPI + esl);
            int s2 = __shfl(myi, i + 2 * EPI + esl);
            int s3 = __shfl(myi, i + 3 * EPI + esl);
            unsigned u0 = x1[(size_t)s0 * C + chunk];
            unsigned u1 = x1[(size_t)s1 * C + chunk];
            unsigned u2 = x1[(size_t)s2 * C + chunk];
            unsigned u3 = x1[(size_t)s3 * C + chunk];
            ACC_U1(u0); ACC_U1(u1); ACC_U1(u2); ACC_U1(u3);
        }
        if (i + 2 * EPI <= take) {
            int s0 = __shfl(myi, i + esl);
            int s1 = __shfl(myi, i + EPI + esl);
            unsigned u0 = x1[(size_t)s0 * C + chunk];
            unsigned u1 = x1[(size_t)s1 * C + chunk];
            ACC_U1(u0); ACC_U1(u1);
            i += 2 * EPI;
        }
        if (i + EPI <= take) {
            int s = __shfl(myi, i + esl);
            unsigned u = x1[(size_t)s * C + chunk];
            ACC_U1(u);
            i += EPI;
        }
        int rem = take - i;
        if (rem > 0) {
            int s = __shfl(myi, i + ((esl < rem) ? esl : 0));
            unsigned u = x1[(size_t)s * C + chunk];
            if (esl < rem) ACC_U1(u);
        }
    }
    #undef ACC_U1
    for (int off = 32; off >= C; off >>= 1) {
        #pragma unroll
        for (int q = 0; q < 2; q++)
            a[q] += __shfl_xor(a[q], off);
    }
}

// ---------- standalone L0 gather: one wave per node -> bf16 agg ----------
__global__ __launch_bounds__(256) void gather_L0(
        const unsigned short* __restrict__ xh, const int* __restrict__ esrc,
        const int* __restrict__ rowptr, unsigned short* __restrict__ aggh /* N x 128 bf16 */) {
    const int wave = threadIdx.x >> 6, lane = threadIdx.x & 63;
    const int node = blockIdx.x * 4 + wave;
    if (node >= NN) return;
    float a[8] = {0, 0, 0, 0, 0, 0, 0, 0};
    int beg = rowptr[node], end = rowptr[node + 1];
    gather_bf16<16>((const uint4*)xh, esrc, beg, end - beg, node, lane, a);
    if (lane < 16) {
        uint4 o;
        o.x = (unsigned)f2bf_rne(a[0]) | ((unsigned)f2bf_rne(a[1]) << 16);
        o.y = (unsigned)f2bf_rne(a[2]) | ((unsigned)f2bf_rne(a[3]) << 16);
        o.z = (unsigned)f2bf_rne(a[4]) | ((unsigned)f2bf_rne(a[5]) << 16);
        o.w = (unsigned)f2bf_rne(a[6]) | ((unsigned)f2bf_rne(a[7]) << 16);
        *(uint4*)&aggh[(size_t)node * 128 + lane * 8] = o;
    }
}

// ---------- L0 GEMM chain via MFMA bf16 (MT=64, 4 waves) ----------
// GEMM1: relu(agg@W1+b1) -> GEMM2: BN(.@W2+b2), relu -> GEMM3: .@W1_1 -> z1h
// MFMA 16x16x32 bf16 layouts: A[m=l&15][k=(l>>4)*8+j], B[k=(l>>4)*8+j][n=l&15],
// D[row=(l>>4)*4+r][col=l&15]  (m89-verified C/D mapping)
__global__ __launch_bounds__(256) void gemm_L0(
        const unsigned short* __restrict__ aggh, unsigned short* __restrict__ z1h,
        const unsigned short* __restrict__ W1t,  // [128n][128k] bf16
        const unsigned short* __restrict__ W2t,  // [128n][128k] bf16
        const unsigned short* __restrict__ W3t,  // [64n][128k] bf16
        const float* __restrict__ b1, const float* __restrict__ b2,
        const float* __restrict__ gamma, const float* __restrict__ beta,
        const float* __restrict__ mean, const float* __restrict__ var) {
    constexpr int MT = 64, LDA = 136;   // bf16 units; 272B row stride -> uniform bank-quad spread
    __shared__ __align__(16) unsigned short shA[MT * LDA];
    __shared__ __align__(16) unsigned short shB[MT * LDA];
    const int tid = threadIdx.x;
    const int wave = tid >> 6, lane = tid & 63;
    const int nodeBase = blockIdx.x * MT;
    const int lr = lane & 15;       // row (A) / col (B,D) within tile
    const int lg = lane >> 4;       // k-group (A,B) / row-group (D)
    const int lk = lg * 8;
    const int n0 = wave * 32;       // this wave's output-column base (GEMM1/2)

    // ---- stage bf16 agg tile -> shA, coalesced 16B ----
    #pragma unroll
    for (int j = 0; j < 4; j++) {
        int f = tid + j * 256;              // uint4 index within tile (1024 total)
        int row = f >> 4, c = f & 15;
        int node = nodeBase + row;
        uint4 v = (node < NN) ? ((const uint4*)aggh)[(size_t)node * 16 + c]
                              : make_uint4(0u, 0u, 0u, 0u);
        *(uint4*)&shA[row * LDA + c * 8] = v;
    }
    __syncthreads();

    f32x4 acc[4][2];

    // ---- GEMM1: h1 = relu(A @ W1 + b1); wave owns cols [n0, n0+32) ----
    {
        float bv0 = b1[n0 + lr], bv1 = b1[n0 + 16 + lr];
        #pragma unroll
        for (int m = 0; m < 4; m++) {
            f32x4 c0 = {bv0, bv0, bv0, bv0};
            f32x4 c1 = {bv1, bv1, bv1, bv1};
            acc[m][0] = c0; acc[m][1] = c1;
        }
        #pragma unroll
        for (int ks = 0; ks < 4; ks++) {
            const int k0 = ks * 32 + lk;
            bf16x8 wb0 = *(const bf16x8*)&W1t[(n0 + lr) * 128 + k0];
            bf16x8 wb1 = *(const bf16x8*)&W1t[(n0 + 16 + lr) * 128 + k0];
            #pragma unroll
            for (int m = 0; m < 4; m++) {
                bf16x8 af = *(const bf16x8*)&shA[(m * 16 + lr) * LDA + k0];
                acc[m][0] = __builtin_amdgcn_mfma_f32_16x16x32_bf16(af, wb0, acc[m][0], 0, 0, 0);
                acc[m][1] = __builtin_amdgcn_mfma_f32_16x16x32_bf16(af, wb1, acc[m][1], 0, 0, 0);
            }
        }
    }
    // relu -> bf16 -> shB (A-layout for GEMM2)
    #pragma unroll
    for (int m = 0; m < 4; m++) {
        #pragma unroll
        for (int nt = 0; nt < 2; nt++) {
            #pragma unroll
            for (int r = 0; r < 4; r++) {
                shB[(m * 16 + lg * 4 + r) * LDA + (n0 + nt * 16 + lr)] =
                    f2bf_rne(fmaxf(acc[m][nt][r], 0.f));
            }
        }
    }
    __syncthreads();

    // ---- GEMM2: h2 = relu(BN(h1 @ W2 + b2)) ----
    {
        float bv0 = b2[n0 + lr], bv1 = b2[n0 + 16 + lr];
        #pragma unroll
        for (int m = 0; m < 4; m++) {
            f32x4 c0 = {bv0, bv0, bv0, bv0};
            f32x4 c1 = {bv1, bv1, bv1, bv1};
            acc[m][0] = c0; acc[m][1] = c1;
        }
        #pragma unroll
        for (int ks = 0; ks < 4; ks++) {
            const int k0 = ks * 32 + lk;
            bf16x8 wb0 = *(const bf16x8*)&W2t[(n0 + lr) * 128 + k0];
            bf16x8 wb1 = *(const bf16x8*)&W2t[(n0 + 16 + lr) * 128 + k0];
            #pragma unroll
            for (int m = 0; m < 4; m++) {
                bf16x8 af = *(const bf16x8*)&shB[(m * 16 + lr) * LDA + k0];
                acc[m][0] = __builtin_amdgcn_mfma_f32_16x16x32_bf16(af, wb0, acc[m][0], 0, 0, 0);
                acc[m][1] = __builtin_amdgcn_mfma_f32_16x16x32_bf16(af, wb1, acc[m][1], 0, 0, 0);
            }
        }
    }
    float s0 = gamma[n0 + lr]      * (1.0f / sqrtf(var[n0 + lr] + 1e-5f));
    float t0 = beta[n0 + lr]       - mean[n0 + lr] * s0;
    float s1 = gamma[n0 + 16 + lr] * (1.0f / sqrtf(var[n0 + 16 + lr] + 1e-5f));
    float t1 = beta[n0 + 16 + lr]  - mean[n0 + 16 + lr] * s1;
    #pragma unroll
    for (int m = 0; m < 4; m++) {
        #pragma unroll
        for (int nt = 0; nt < 2; nt++) {
            float sc = nt ? s1 : s0, sf = nt ? t1 : t0;
            #pragma unroll
            for (int r = 0; r < 4; r++) {
                float y = fmaxf(fmaf(acc[m][nt][r], sc, sf), 0.f);
                shA[(m * 16 + lg * 4 + r) * LDA + (n0 + nt * 16 + lr)] = f2bf_rne(y);
            }
        }
    }
    __syncthreads();

    // ---- GEMM3: z1 = h2 @ W1_1 (no bias/act); wave owns cols [wave*16, +16) ----
    f32x4 a3[4];
    #pragma unroll
    for (int m = 0; m < 4; m++) {
        f32x4 z = {0.f, 0.f, 0.f, 0.f};
        a3[m] = z;
    }
    #pragma unroll
    for (int ks = 0; ks < 4; ks++) {
        const int k0 = ks * 32 + lk;
        bf16x8 wb = *(const bf16x8*)&W3t[(wave * 16 + lr) * 128 + k0];
        #pragma unroll
        for (int m = 0; m < 4; m++) {
            bf16x8 af = *(const bf16x8*)&shA[(m * 16 + lr) * LDA + k0];
            a3[m] = __builtin_amdgcn_mfma_f32_16x16x32_bf16(af, wb, a3[m], 0, 0, 0);
        }
    }
    #pragma unroll
    for (int m = 0; m < 4; m++) {
        #pragma unroll
        for (int r = 0; r < 4; r++) {
            int node = nodeBase + m * 16 + lg * 4 + r;
            if (node < NN)
                z1h[(size_t)node * 64 + wave * 16 + lr] = f2bf_rne(a3[m][r]);
        }
    }
}

// ---------- fused layer 1 (MT=32): u2-gather z1(64) -> +b1,relu -> W2_1+BN+relu -> xW1_2 -> z2h ----------
__global__ __launch_bounds__(256) void fused_L1(
        const unsigned short* __restrict__ z1h, const int* __restrict__ esrc,
        const int* __restrict__ rowptr, unsigned short* __restrict__ z2h,
        const float* __restrict__ b1, const float* __restrict__ W2,
        const float* __restrict__ b2, const float* __restrict__ gamma,
        const float* __restrict__ beta, const float* __restrict__ mean,
        const float* __restrict__ var, const float* __restrict__ Wn /* W1_2: 64x32 */) {
    constexpr int MT = 32, LD = 68;
    __shared__ float sh[MT * LD];
    const int tid = threadIdx.x, wave = tid >> 6, lane = tid & 63;
    const int nodeBase = blockIdx.x * MT;

    for (int r = wave; r < MT; r += 4) {
        int node = nodeBase + r;
        float a[4] = {0, 0, 0, 0};
        if (node < NN) {
            int beg = rowptr[node], end = rowptr[node + 1];
            gather_bf16_u2<16>((const uint2*)z1h, esrc, beg, end - beg, node, lane, a);
        }
        if (lane < 16) {
            float4 b0 = *(const float4*)&b1[lane * 4];
            *(float4*)&sh[r * LD + lane * 4] = make_float4(
                fmaxf(a[0] + b0.x, 0.f), fmaxf(a[1] + b0.y, 0.f),
                fmaxf(a[2] + b0.z, 0.f), fmaxf(a[3] + b0.w, 0.f));
        }
    }
    __syncthreads();

    // GEMM_A: 64->64 (W2_1) + BN + relu. CT=16, RT=16, RPT=2
    const int colid = tid % 16, rowid = tid / 16;
    const int c0 = colid * 4, r0 = rowid * 2;
    float acc[2][4];
    {
        float4 bv = *(const float4*)&b2[c0];
        #pragma unroll
        for (int i = 0; i < 2; i++) {
            acc[i][0] = bv.x; acc[i][1] = bv.y; acc[i][2] = bv.z; acc[i][3] = bv.w;
        }
        #pragma unroll 2
        for (int k4 = 0; k4 < 16; k4++) {
            float4 w[4];
            #pragma unroll
            for (int kk = 0; kk < 4; kk++)
                w[kk] = *(const float4*)&W2[(k4 * 4 + kk) * 64 + c0];
            #pragma unroll
            for (int i = 0; i < 2; i++) {
                float4 a = *(const float4*)&sh[(r0 + i) * LD + k4 * 4];
                const float av[4] = {a.x, a.y, a.z, a.w};
                #pragma unroll
                for (int kk = 0; kk < 4; kk++) {
                    const float* wp = (const float*)&w[kk];
                    #pragma unroll
                    for (int j = 0; j < 4; j++)
                        acc[i][j] = fmaf(av[kk], wp[j], acc[i][j]);
                }
            }
        }
    }
    float4 gv = *(const float4*)&gamma[c0];
    float4 bev = *(const float4*)&beta[c0];
    float4 mv = *(const float4*)&mean[c0];
    float4 vv = *(const float4*)&var[c0];
    float scale[4], shift[4];
    {
        const float* gp = (const float*)&gv; const float* bp = (const float*)&bev;
        const float* mp = (const float*)&mv; const float* vp = (const float*)&vv;
        #pragma unroll
        for (int j = 0; j < 4; j++) {
            scale[j] = gp[j] * (1.0f / sqrtf(vp[j] + 1e-5f));
            shift[j] = bp[j] - mp[j] * scale[j];
        }
    }
    __syncthreads();
    #pragma unroll
    for (int i = 0; i < 2; i++) {
        float4 y;
        y.x = fmaxf(fmaf(acc[i][0], scale[0], shift[0]), 0.f);
        y.y = fmaxf(fmaf(acc[i][1], scale[1], shift[1]), 0.f);
        y.z = fmaxf(fmaf(acc[i][2], scale[2], shift[2]), 0.f);
        y.w = fmaxf(fmaf(acc[i][3], scale[3], shift[3]), 0.f);
        *(float4*)&sh[(r0 + i) * LD + c0] = y;
    }
    __syncthreads();

    // GEMM_B: y(64) @ W1_2(64x32) -> z2 (bf16). CT=8, RT=32, RPT=1
    {
        const int colid2 = tid % 8, rowid2 = tid / 8;
        const int c0b = colid2 * 4, r0b = rowid2;
        float a3[4] = {};
        #pragma unroll 2
        for (int k4 = 0; k4 < 16; k4++) {
            float4 w[4];
            #pragma unroll
            for (int kk = 0; kk < 4; kk++)
                w[kk] = *(const float4*)&Wn[(k4 * 4 + kk) * 32 + c0b];
            float4 a = *(const float4*)&sh[r0b * LD + k4 * 4];
            const float av[4] = {a.x, a.y, a.z, a.w};
            #pragma unroll
            for (int kk = 0; kk < 4; kk++) {
                const float* wp = (const float*)&w[kk];
                #pragma unroll
                for (int j = 0; j < 4; j++)
                    a3[j] = fmaf(av[kk], wp[j], a3[j]);
            }
        }
        int node = nodeBase + r0b;
        if (node < NN) {
            ushort4 o;
            o.x = f2bf_rne(a3[0]); o.y = f2bf_rne(a3[1]);
            o.z = f2bf_rne(a3[2]); o.w = f2bf_rne(a3[3]);
            *(ushort4*)&z2h[(size_t)node * 32 + c0b] = o;
        }
    }
}

// ---------- fused layer 2 (MT=32): u1-gather z2(32) -> +b1,relu -> W2_2+BN -> xW_lin -> logits ----------
__global__ __launch_bounds__(256) void fused_L2(
        const unsigned short* __restrict__ z2h, const int* __restrict__ esrc,
        const int* __restrict__ rowptr, float* __restrict__ logits,
        const float* __restrict__ b1, const float* __restrict__ W2,
        const float* __restrict__ b2, const float* __restrict__ gamma,
        const float* __restrict__ beta, const float* __restrict__ mean,
        const float* __restrict__ var, const float* __restrict__ Wl,
        const float* __restrict__ bl) {
    constexpr int MT = 32, LD = 36;
    __shared__ float sh[MT * LD];
    const int tid = threadIdx.x, wave = tid >> 6, lane = tid & 63;
    const int nodeBase = blockIdx.x * MT;

    for (int r = wave; r < MT; r += 4) {
        int node = nodeBase + r;
        float a[2] = {0, 0};
        if (node < NN) {
            int beg = rowptr[node], end = rowptr[node + 1];
            gather_bf16_u1<16>((const unsigned*)z2h, esrc, beg, end - beg, node, lane, a);
        }
        if (lane < 16) {
            float2 bv = *(const float2*)&b1[lane * 2];
            *(float2*)&sh[r * LD + lane * 2] = make_float2(
                fmaxf(a[0] + bv.x, 0.f), fmaxf(a[1] + bv.y, 0.f));
        }
    }
    __syncthreads();

    // GEMM: 32->32 (W2_2) + BN (no relu), dot W_lin. CT=8, RT=32, RPT=1
    const int colid = tid % 8, rowid = tid / 8;
    const int c0 = colid * 4, r0 = rowid;
    float acc[4];
    {
        float4 bv = *(const float4*)&b2[c0];
        acc[0] = bv.x; acc[1] = bv.y; acc[2] = bv.z; acc[3] = bv.w;
        #pragma unroll
        for (int k4 = 0; k4 < 8; k4++) {
            float4 w[4];
            #pragma unroll
            for (int kk = 0; kk < 4; kk++)
                w[kk] = *(const float4*)&W2[(k4 * 4 + kk) * 32 + c0];
            float4 a = *(const float4*)&sh[r0 * LD + k4 * 4];
            const float av[4] = {a.x, a.y, a.z, a.w};
            #pragma unroll
            for (int kk = 0; kk < 4; kk++) {
                const float* wp = (const float*)&w[kk];
                #pragma unroll
                for (int j = 0; j < 4; j++)
                    acc[j] = fmaf(av[kk], wp[j], acc[j]);
            }
        }
    }
    float4 gv = *(const float4*)&gamma[c0];
    float4 bev = *(const float4*)&beta[c0];
    float4 mv = *(const float4*)&mean[c0];
    float4 vv = *(const float4*)&var[c0];
    float4 wl = *(const float4*)&Wl[c0];
    float p = 0.f;
    {
        const float* gp = (const float*)&gv; const float* bp = (const float*)&bev;
        const float* mp = (const float*)&mv; const float* vp = (const float*)&vv;
        const float* wp = (const float*)&wl;
        #pragma unroll
        for (int j = 0; j < 4; j++) {
            float sc = gp[j] * (1.0f / sqrtf(vp[j] + 1e-5f));
            float y = (acc[j] - mp[j]) * sc + bp[j];
            p = fmaf(y, wp[j], p);
        }
    }
    p += __shfl_xor(p, 1);
    p += __shfl_xor(p, 2);
    p += __shfl_xor(p, 4);
    int node = nodeBase + r0;
    if ((tid & 7) == 0 && node < NN)
        logits[node] = (p + bl[0]) * 0.2f;
}

// ---------- head ----------
__global__ __launch_bounds__(256) void seg_softmax(
        const float* __restrict__ logits, const int* __restrict__ gstart,
        float* __restrict__ out) {
    __shared__ float slog[1024];
    __shared__ float sred[4];
    __shared__ float sbc[2];
    int g = blockIdx.x;
    int beg = gstart[g], end = gstart[g + 1];
    int cnt = end - beg;
    int t = threadIdx.x;
    if (cnt <= 0) return;
    bool fits = (cnt <= 1024);

    float lmax = -3.402823466e+38f;
    for (int i = t; i < cnt; i += 256) {
        float lg = logits[beg + i];
        if (fits) slog[i] = lg;
        lmax = fmaxf(lmax, lg);
    }
    #pragma unroll
    for (int off = 32; off > 0; off >>= 1)
        lmax = fmaxf(lmax, __shfl_down(lmax, off));
    if ((t & 63) == 0) sred[t >> 6] = lmax;
    __syncthreads();
    if (t == 0) sbc[0] = fmaxf(fmaxf(sred[0], sred[1]), fmaxf(sred[2], sred[3]));
    __syncthreads();
    float gm = sbc[0];

    float lsum = 0.f;
    for (int i = t; i < cnt; i += 256) {
        float lg = fits ? slog[i] : logits[beg + i];
        float e = expf(lg - gm);
        if (fits) slog[i] = e;
        lsum += e;
    }
    #pragma unroll
    for (int off = 32; off > 0; off >>= 1)
        lsum += __shfl_down(lsum, off);
    __syncthreads();
    if ((t & 63) == 0) sred[t >> 6] = lsum;
    __syncthreads();
    if (t == 0) sbc[1] = (sred[0] + sred[1]) + (sred[2] + sred[3]);
    __syncthreads();
    float inv = 1.0f / sbc[1];

    for (int i = t; i < cnt; i += 256) {
        float e = fits ? slog[i] : expf(logits[beg + i] - gm);
        out[beg + i] = e * inv;
    }
}

// ---------- launch ----------
extern "C" void kernel_launch(void* const* d_in, const int* in_sizes, int n_in,
                              void* d_out, int out_size, void* d_ws, size_t ws_size,
                              hipStream_t stream) {
    const float* x    = (const float*)d_in[0];
    const int*   ei   = (const int*)d_in[1];
    const int*   srcI = ei;
    const int*   dstI = ei + NE;
    const int*   batch = (const int*)d_in[2];

    const float* P[29];
    for (int i = 0; i < 29; i++) P[i] = (const float*)d_in[i];
    const float* Wlin = P[27];
    const float* blin = P[28];

    unsigned short* xh  = (unsigned short*)d_ws;       // N x 128 bf16
    unsigned short* z1h = xh + (size_t)NN * 128;       // N x 64 bf16
    unsigned short* z2h = z1h + (size_t)NN * 64;       // N x 32 bf16
    float* logits = (float*)(z2h + (size_t)NN * 32);   // N
    int* gstart = (int*)(logits + NN);                 // NG+1
    int* deg    = gstart + NG + 1;                     // N
    int* iscan  = deg + NN;                            // N
    int* rowptr = iscan + NN;                          // N+1
    int* bsum   = rowptr + NN + 1;                     // NB
    int* boff   = bsum + NB;                           // NB
    int* eoff   = boff + NB;                           // E
    int* esrc   = eoff + NE;                           // E
    uintptr_t pal = ((uintptr_t)(esrc + NE) + 255) & ~(uintptr_t)255;
    unsigned short* aggh = (unsigned short*)pal;       // N x 128 bf16 (16B-aligned)
    unsigned short* W1t  = aggh + (size_t)NN * 128;    // 128x128 bf16 [n][k]
    unsigned short* W2t  = W1t + 16384;                // 128x128 bf16 [n][k]
    unsigned short* W3t  = W2t + 16384;                // 64x128 bf16 [n][k]
    float* outp = (float*)d_out;

    const int TB = 256;

    // ---- merged convert + CSR histogram (grid covers N4 > NE) ----
    hipMemsetAsync(deg, 0, NN * sizeof(int), stream);
    conv_hist<<<(N4 + TB - 1) / TB, TB, 0, stream>>>(
        (const float4*)x, (ushort4*)xh, dstI, deg, eoff);

    block_scan<<<NB, 256, 0, stream>>>(deg, iscan, bsum,
        P[3], P[5], P[11], W1t, W2t, W3t);
    scan_bsum<<<1, 256, 0, stream>>>(bsum, boff);
    finalize_bounds<<<NB, 256, 0, stream>>>(deg, iscan, boff, rowptr, batch, gstart);
    fill_csr2<<<(NE + TB - 1) / TB, TB, 0, stream>>>(srcI, dstI, rowptr, eoff, esrc);

    const int GB  = (NN + 3) / 4;      // gather_L0: 1 wave/node
    const int FB64 = (NN + 63) / 64;
    const int FB32 = (NN + 31) / 32;

    gather_L0<<<GB, 256, 0, stream>>>(xh, esrc, rowptr, aggh);
    gemm_L0<<<FB64, 256, 0, stream>>>(aggh, z1h, W1t, W2t, W3t,
        P[4], P[6], P[7], P[8], P[9], P[10]);
    fused_L1<<<FB32, 256, 0, stream>>>(z1h, esrc, rowptr, z2h,
        P[12], P[13], P[14], P[15], P[16], P[17], P[18], P[19]);
    fused_L2<<<FB32, 256, 0, stream>>>(z2h, esrc, rowptr, logits,
        P[20], P[21], P[22], P[23], P[24], P[25], P[26], Wlin, blin);

    seg_softmax<<<NG, 256, 0, stream>>>(logits, gstart, outp);
}

// Round 4
// 285.618 us; speedup vs baseline: 1.2953x; 1.0698x over previous
//
#include <hip/hip_runtime.h>

#define NN 50000
#define NE 800000
#define NG 256
#define NB ((NN + 255) / 256)   // scan blocks
#define N4 (NN * 128 / 4)       // float4 count of x (1.6M)

typedef __attribute__((ext_vector_type(8))) short bf16x8;
typedef __attribute__((ext_vector_type(4))) float f32x4;

// ---------- bf16 helpers ----------
__device__ __forceinline__ unsigned short f2bf_rne(float f) {
    unsigned u = __float_as_uint(f);
    u += 0x7fffu + ((u >> 16) & 1u);   // round-to-nearest-even
    return (unsigned short)(u >> 16);
}
#define BF2F_LO(u) __uint_as_float((u) << 16)
#define BF2F_HI(u) __uint_as_float((u) & 0xffff0000u)

// ---------- merged: x->bf16 convert + degree histogram (deg pre-zeroed) ----------
__global__ void conv_hist(const float4* __restrict__ x, ushort4* __restrict__ xh,
                          const int* __restrict__ dst, int* __restrict__ deg,
                          int* __restrict__ eoff) {
    int i = blockIdx.x * 256 + threadIdx.x;
    if (i < N4) {
        float4 v = x[i];
        ushort4 o;
        o.x = f2bf_rne(v.x); o.y = f2bf_rne(v.y);
        o.z = f2bf_rne(v.z); o.w = f2bf_rne(v.w);
        xh[i] = o;
    }
    if (i < NE) eoff[i] = atomicAdd(&deg[dst[i]], 1);
}

// ---------- CSR scan (+ weight transpose/convert for MFMA gemms) ----------
__global__ void block_scan(const int* __restrict__ deg, int* __restrict__ iscan,
                           int* __restrict__ bsum,
                           const float* __restrict__ W1, const float* __restrict__ W2,
                           const float* __restrict__ W3,
                           const float* __restrict__ W21, const float* __restrict__ W12,
                           unsigned short* __restrict__ W1t,
                           unsigned short* __restrict__ W2t,
                           unsigned short* __restrict__ W3t,
                           unsigned short* __restrict__ W21t,
                           unsigned short* __restrict__ W12t) {
    // weight prep: Wt[n][k] = bf16(W[k][n]) (independent side-work)
    int gidx = blockIdx.x * 256 + threadIdx.x;
    if (gidx < 16384) {
        int n = gidx >> 7, k = gidx & 127;
        W1t[gidx] = f2bf_rne(W1[k * 128 + n]);
        W2t[gidx] = f2bf_rne(W2[k * 128 + n]);
    } else if (gidx < 24576) {
        int i2 = gidx - 16384;
        int n = i2 >> 7, k = i2 & 127;      // n in [0,64), k in [0,128)
        W3t[i2] = f2bf_rne(W3[k * 64 + n]);
    } else if (gidx < 28672) {
        int i3 = gidx - 24576;
        int n = i3 >> 6, k = i3 & 63;       // 64x64
        W21t[i3] = f2bf_rne(W21[k * 64 + n]);
    } else if (gidx < 30720) {
        int i4 = gidx - 28672;
        int n = i4 >> 6, k = i4 & 63;       // n in [0,32), k in [0,64)
        W12t[i4] = f2bf_rne(W12[k * 32 + n]);
    }

    __shared__ int sh[256];
    int t = threadIdx.x;
    int i = blockIdx.x * 256 + t;
    int v = (i < NN) ? deg[i] : 0;
    sh[t] = v;
    __syncthreads();
    #pragma unroll
    for (int off = 1; off < 256; off <<= 1) {
        int add = (t >= off) ? sh[t - off] : 0;
        __syncthreads();
        sh[t] += add;
        __syncthreads();
    }
    if (i < NN) iscan[i] = sh[t];
    if (t == 255) bsum[blockIdx.x] = sh[255];
}

__global__ void scan_bsum(const int* __restrict__ bsum, int* __restrict__ boff) {
    __shared__ int sh[256];
    int t = threadIdx.x;
    int v = (t < NB) ? bsum[t] : 0;
    sh[t] = v;
    __syncthreads();
    #pragma unroll
    for (int off = 1; off < 256; off <<= 1) {
        int add = (t >= off) ? sh[t - off] : 0;
        __syncthreads();
        sh[t] += add;
        __syncthreads();
    }
    if (t < NB) boff[t] = sh[t] - v;  // exclusive
}

// merged: rowptr finalize + graph-bounds (batch is sorted)
__global__ void finalize_bounds(const int* __restrict__ deg, const int* __restrict__ iscan,
                                const int* __restrict__ boff, int* __restrict__ rowptr,
                                const int* __restrict__ batch, int* __restrict__ gstart) {
    int i = blockIdx.x * 256 + threadIdx.x;
    if (i < NN) {
        rowptr[i] = iscan[i] - deg[i] + boff[blockIdx.x];
        int b = batch[i];
        if (i == 0) {
            for (int g = 0; g <= b; g++) gstart[g] = 0;
        } else {
            int p = batch[i - 1];
            for (int g = p + 1; g <= b; g++) gstart[g] = i;
        }
        if (i == NN - 1) {
            for (int g = b + 1; g <= NG; g++) gstart[g] = NN;
        }
    }
    if (i == 0) rowptr[NN] = NE;
}

__global__ void fill_csr2(const int* __restrict__ src, const int* __restrict__ dst,
                          const int* __restrict__ rowptr, const int* __restrict__ eoff,
                          int* __restrict__ esrc) {
    int e = blockIdx.x * blockDim.x + threadIdx.x;
    if (e >= NE) return;
    esrc[rowptr[dst[e]] + eoff[e]] = src[e];
}

// ---------- bf16 wave-cooperative gathers ----------
// C lane-chunks per row, EPI = 64/C edges per pass; 4x/2x/1x unroll keeps
// up to 4 independent loads in flight.

// 16B-lane variant (rows = 256B): x (128 cols)
template <int C4>
__device__ __forceinline__ void gather_bf16(const uint4* __restrict__ x4,
                                            const int* __restrict__ esrc,
                                            int beg, int cnt, int node, int lane,
                                            float* a /* [8] */) {
    constexpr int EPI = 64 / C4;
    const int chunk = lane & (C4 - 1);
    const int esl   = lane / C4;
    #define ACC_U4(u) do { \
        a[0] += BF2F_LO((u).x); a[1] += BF2F_HI((u).x); \
        a[2] += BF2F_LO((u).y); a[3] += BF2F_HI((u).y); \
        a[4] += BF2F_LO((u).z); a[5] += BF2F_HI((u).z); \
        a[6] += BF2F_LO((u).w); a[7] += BF2F_HI((u).w); } while (0)
    if (esl == 0) { uint4 u = x4[(size_t)node * C4 + chunk]; ACC_U4(u); }
    for (int c = 0; c < cnt; c += 64) {
        int take = min(64, cnt - c);
        int myi = (lane < take) ? esrc[beg + c + lane] : 0;
        int i = 0;
        for (; i + 4 * EPI <= take; i += 4 * EPI) {
            int s0 = __shfl(myi, i + esl);
            int s1 = __shfl(myi, i + EPI + esl);
            int s2 = __shfl(myi, i + 2 * EPI + esl);
            int s3 = __shfl(myi, i + 3 * EPI + esl);
            uint4 u0 = x4[(size_t)s0 * C4 + chunk];
            uint4 u1 = x4[(size_t)s1 * C4 + chunk];
            uint4 u2 = x4[(size_t)s2 * C4 + chunk];
            uint4 u3 = x4[(size_t)s3 * C4 + chunk];
            ACC_U4(u0); ACC_U4(u1); ACC_U4(u2); ACC_U4(u3);
        }
        if (i + 2 * EPI <= take) {
            int s0 = __shfl(myi, i + esl);
            int s1 = __shfl(myi, i + EPI + esl);
            uint4 u0 = x4[(size_t)s0 * C4 + chunk];
            uint4 u1 = x4[(size_t)s1 * C4 + chunk];
            ACC_U4(u0); ACC_U4(u1);
            i += 2 * EPI;
        }
        if (i + EPI <= take) {
            int s = __shfl(myi, i + esl);
            uint4 u = x4[(size_t)s * C4 + chunk];
            ACC_U4(u);
            i += EPI;
        }
        int rem = take - i;
        if (rem > 0) {
            int s = __shfl(myi, i + ((esl < rem) ? esl : 0));
            uint4 u = x4[(size_t)s * C4 + chunk];
            if (esl < rem) ACC_U4(u);
        }
    }
    #undef ACC_U4
    for (int off = 32; off >= C4; off >>= 1) {
        #pragma unroll
        for (int q = 0; q < 8; q++)
            a[q] += __shfl_xor(a[q], off);
    }
}

// 8B-lane variant (rows = 128B): z1 (64 cols). C=16, EPI=4.
template <int C>
__device__ __forceinline__ void gather_bf16_u2(const uint2* __restrict__ x2,
                                               const int* __restrict__ esrc,
                                               int beg, int cnt, int node, int lane,
                                               float* a /* [4] */) {
    constexpr int EPI = 64 / C;
    const int chunk = lane & (C - 1);
    const int esl   = lane / C;
    #define ACC_U2(u) do { \
        a[0] += BF2F_LO((u).x); a[1] += BF2F_HI((u).x); \
        a[2] += BF2F_LO((u).y); a[3] += BF2F_HI((u).y); } while (0)
    if (esl == 0) { uint2 u = x2[(size_t)node * C + chunk]; ACC_U2(u); }
    for (int c = 0; c < cnt; c += 64) {
        int take = min(64, cnt - c);
        int myi = (lane < take) ? esrc[beg + c + lane] : 0;
        int i = 0;
        for (; i + 4 * EPI <= take; i += 4 * EPI) {
            int s0 = __shfl(myi, i + esl);
            int s1 = __shfl(myi, i + EPI + esl);
            int s2 = __shfl(myi, i + 2 * EPI + esl);
            int s3 = __shfl(myi, i + 3 * EPI + esl);
            uint2 u0 = x2[(size_t)s0 * C + chunk];
            uint2 u1 = x2[(size_t)s1 * C + chunk];
            uint2 u2 = x2[(size_t)s2 * C + chunk];
            uint2 u3 = x2[(size_t)s3 * C + chunk];
            ACC_U2(u0); ACC_U2(u1); ACC_U2(u2); ACC_U2(u3);
        }
        if (i + 2 * EPI <= take) {
            int s0 = __shfl(myi, i + esl);
            int s1 = __shfl(myi, i + EPI + esl);
            uint2 u0 = x2[(size_t)s0 * C + chunk];
            uint2 u1 = x2[(size_t)s1 * C + chunk];
            ACC_U2(u0); ACC_U2(u1);
            i += 2 * EPI;
        }
        if (i + EPI <= take) {
            int s = __shfl(myi, i + esl);
            uint2 u = x2[(size_t)s * C + chunk];
            ACC_U2(u);
            i += EPI;
        }
        int rem = take - i;
        if (rem > 0) {
            int s = __shfl(myi, i + ((esl < rem) ? esl : 0));
            uint2 u = x2[(size_t)s * C + chunk];
            if (esl < rem) ACC_U2(u);
        }
    }
    #undef ACC_U2
    for (int off = 32; off >= C; off >>= 1) {
        #pragma unroll
        for (int q = 0; q < 4; q++)
            a[q] += __shfl_xor(a[q], off);
    }
}

// 4B-lane variant (rows = 64B): z2 (32 cols). C=16, EPI=4.
template <int C>
__device__ __forceinline__ void gather_bf16_u1(const unsigned* __restrict__ x1,
                                               const int* __restrict__ esrc,
                                               int beg, int cnt, int node, int lane,
                                               float* a /* [2] */) {
    constexpr int EPI = 64 / C;
    const int chunk = lane & (C - 1);
    const int esl   = lane / C;
    #define ACC_U1(u) do { \
        a[0] += BF2F_LO(u); a[1] += BF2F_HI(u); } while (0)
    if (esl == 0) { unsigned u = x1[(size_t)node * C + chunk]; ACC_U1(u); }
    for (int c = 0; c < cnt; c += 64) {
        int take = min(64, cnt - c);
        int myi = (lane < take) ? esrc[beg + c + lane] : 0;
        int i = 0;
        for (; i + 4 * EPI <= take; i += 4 * EPI) {
            int s0 = __shfl(myi, i + esl);
            int s1 = __shfl(myi, i + EPI + esl);
            int s2 = __shfl(myi, i + 2 * EPI + esl);
            int s3 = __shfl(myi, i + 3 * EPI + esl);
            unsigned u0 = x1[(size_t)s0 * C + chunk];
            unsigned u1 = x1[(size_t)s1 * C + chunk];
            unsigned u2 = x1[(size_t)s2 * C + chunk];
            unsigned u3 = x1[(size_t)s3 * C + chunk];
            ACC_U1(u0); ACC_U1(u1); ACC_U1(u2); ACC_U1(u3);
        }
        if (i + 2 * EPI <= take) {
            int s0 = __shfl(myi, i + esl);
            int s1 = __shfl(myi, i + EPI + esl);
            unsigned u0 = x1[(size_t)s0 * C + chunk];
            unsigned u1 = x1[(size_t)s1 * C + chunk];
            ACC_U1(u0); ACC_U1(u1);
            i += 2 * EPI;
        }
        if (i + EPI <= take) {
            int s = __shfl(myi, i + esl);
            unsigned u = x1[(size_t)s * C + chunk];
            ACC_U1(u);
            i += EPI;
        }
        int rem = take - i;
        if (rem > 0) {
            int s = __shfl(myi, i + ((esl < rem) ? esl : 0));
            unsigned u = x1[(size_t)s * C + chunk];
            if (esl < rem) ACC_U1(u);
        }
    }
    #undef ACC_U1
    for (int off = 32; off >= C; off >>= 1) {
        #pragma unroll
        for (int q = 0; q < 2; q++)
            a[q] += __shfl_xor(a[q], off);
    }
}

// ---------- L0 gather: one wave per node -> bf16 agg ----------
__global__ __launch_bounds__(256) void gather_L0(
        const unsigned short* __restrict__ xh, const int* __restrict__ esrc,
        const int* __restrict__ rowptr, unsigned short* __restrict__ aggh /* N x 128 bf16 */) {
    const int wave = threadIdx.x >> 6, lane = threadIdx.x & 63;
    const int node = blockIdx.x * 4 + wave;
    if (node >= NN) return;
    float a[8] = {0, 0, 0, 0, 0, 0, 0, 0};
    int beg = rowptr[node], end = rowptr[node + 1];
    gather_bf16<16>((const uint4*)xh, esrc, beg, end - beg, node, lane, a);
    if (lane < 16) {
        uint4 o;
        o.x = (unsigned)f2bf_rne(a[0]) | ((unsigned)f2bf_rne(a[1]) << 16);
        o.y = (unsigned)f2bf_rne(a[2]) | ((unsigned)f2bf_rne(a[3]) << 16);
        o.z = (unsigned)f2bf_rne(a[4]) | ((unsigned)f2bf_rne(a[5]) << 16);
        o.w = (unsigned)f2bf_rne(a[6]) | ((unsigned)f2bf_rne(a[7]) << 16);
        *(uint4*)&aggh[(size_t)node * 128 + lane * 8] = o;
    }
}

// ---------- L1 gather: one wave per node; +b1, relu -> bf16 agg1 ----------
__global__ __launch_bounds__(256) void gather_L1(
        const unsigned short* __restrict__ z1h, const int* __restrict__ esrc,
        const int* __restrict__ rowptr, const float* __restrict__ b1,
        unsigned short* __restrict__ agg1h /* N x 64 bf16 */) {
    const int wave = threadIdx.x >> 6, lane = threadIdx.x & 63;
    const int node = blockIdx.x * 4 + wave;
    if (node >= NN) return;
    float a[4] = {0, 0, 0, 0};
    int beg = rowptr[node], end = rowptr[node + 1];
    gather_bf16_u2<16>((const uint2*)z1h, esrc, beg, end - beg, node, lane, a);
    if (lane < 16) {
        float4 bv = *(const float4*)&b1[lane * 4];
        uint2 o;
        o.x = (unsigned)f2bf_rne(fmaxf(a[0] + bv.x, 0.f)) |
              ((unsigned)f2bf_rne(fmaxf(a[1] + bv.y, 0.f)) << 16);
        o.y = (unsigned)f2bf_rne(fmaxf(a[2] + bv.z, 0.f)) |
              ((unsigned)f2bf_rne(fmaxf(a[3] + bv.w, 0.f)) << 16);
        *(uint2*)&agg1h[(size_t)node * 64 + lane * 4] = o;
    }
}

// ---------- L2 gather: one wave per node; +b1, relu -> bf16 agg2 ----------
__global__ __launch_bounds__(256) void gather_L2(
        const unsigned short* __restrict__ z2h, const int* __restrict__ esrc,
        const int* __restrict__ rowptr, const float* __restrict__ b1,
        unsigned short* __restrict__ agg2h /* N x 32 bf16 */) {
    const int wave = threadIdx.x >> 6, lane = threadIdx.x & 63;
    const int node = blockIdx.x * 4 + wave;
    if (node >= NN) return;
    float a[2] = {0, 0};
    int beg = rowptr[node], end = rowptr[node + 1];
    gather_bf16_u1<16>((const unsigned*)z2h, esrc, beg, end - beg, node, lane, a);
    if (lane < 16) {
        float2 bv = *(const float2*)&b1[lane * 2];
        unsigned o = (unsigned)f2bf_rne(fmaxf(a[0] + bv.x, 0.f)) |
                     ((unsigned)f2bf_rne(fmaxf(a[1] + bv.y, 0.f)) << 16);
        *(unsigned*)&agg2h[(size_t)node * 32 + lane * 2] = o;
    }
}

// ---------- L0 GEMM chain via MFMA bf16 (MT=64, 4 waves) ----------
// GEMM1: relu(agg@W1+b1) -> GEMM2: BN(.@W2+b2), relu -> GEMM3: .@W1_1 -> z1h
// MFMA 16x16x32 bf16 layouts: A[m=l&15][k=(l>>4)*8+j], B[k=(l>>4)*8+j][n=l&15],
// D[row=(l>>4)*4+r][col=l&15]  (m89-verified C/D mapping)
__global__ __launch_bounds__(256) void gemm_L0(
        const unsigned short* __restrict__ aggh, unsigned short* __restrict__ z1h,
        const unsigned short* __restrict__ W1t,  // [128n][128k] bf16
        const unsigned short* __restrict__ W2t,  // [128n][128k] bf16
        const unsigned short* __restrict__ W3t,  // [64n][128k] bf16
        const float* __restrict__ b1, const float* __restrict__ b2,
        const float* __restrict__ gamma, const float* __restrict__ beta,
        const float* __restrict__ mean, const float* __restrict__ var) {
    constexpr int MT = 64, LDA = 136;   // bf16 units; 272B row stride
    __shared__ __align__(16) unsigned short shA[MT * LDA];
    __shared__ __align__(16) unsigned short shB[MT * LDA];
    const int tid = threadIdx.x;
    const int wave = tid >> 6, lane = tid & 63;
    const int nodeBase = blockIdx.x * MT;
    const int lr = lane & 15;
    const int lg = lane >> 4;
    const int lk = lg * 8;
    const int n0 = wave * 32;

    // stage bf16 agg tile -> shA, coalesced 16B
    #pragma unroll
    for (int j = 0; j < 4; j++) {
        int f = tid + j * 256;
        int row = f >> 4, c = f & 15;
        int node = nodeBase + row;
        uint4 v = (node < NN) ? ((const uint4*)aggh)[(size_t)node * 16 + c]
                              : make_uint4(0u, 0u, 0u, 0u);
        *(uint4*)&shA[row * LDA + c * 8] = v;
    }
    __syncthreads();

    f32x4 acc[4][2];

    // GEMM1: h1 = relu(A @ W1 + b1); wave owns cols [n0, n0+32)
    {
        float bv0 = b1[n0 + lr], bv1 = b1[n0 + 16 + lr];
        #pragma unroll
        for (int m = 0; m < 4; m++) {
            f32x4 c0 = {bv0, bv0, bv0, bv0};
            f32x4 c1 = {bv1, bv1, bv1, bv1};
            acc[m][0] = c0; acc[m][1] = c1;
        }
        #pragma unroll
        for (int ks = 0; ks < 4; ks++) {
            const int k0 = ks * 32 + lk;
            bf16x8 wb0 = *(const bf16x8*)&W1t[(n0 + lr) * 128 + k0];
            bf16x8 wb1 = *(const bf16x8*)&W1t[(n0 + 16 + lr) * 128 + k0];
            #pragma unroll
            for (int m = 0; m < 4; m++) {
                bf16x8 af = *(const bf16x8*)&shA[(m * 16 + lr) * LDA + k0];
                acc[m][0] = __builtin_amdgcn_mfma_f32_16x16x32_bf16(af, wb0, acc[m][0], 0, 0, 0);
                acc[m][1] = __builtin_amdgcn_mfma_f32_16x16x32_bf16(af, wb1, acc[m][1], 0, 0, 0);
            }
        }
    }
    #pragma unroll
    for (int m = 0; m < 4; m++) {
        #pragma unroll
        for (int nt = 0; nt < 2; nt++) {
            #pragma unroll
            for (int r = 0; r < 4; r++) {
                shB[(m * 16 + lg * 4 + r) * LDA + (n0 + nt * 16 + lr)] =
                    f2bf_rne(fmaxf(acc[m][nt][r], 0.f));
            }
        }
    }
    __syncthreads();

    // GEMM2: h2 = relu(BN(h1 @ W2 + b2))
    {
        float bv0 = b2[n0 + lr], bv1 = b2[n0 + 16 + lr];
        #pragma unroll
        for (int m = 0; m < 4; m++) {
            f32x4 c0 = {bv0, bv0, bv0, bv0};
            f32x4 c1 = {bv1, bv1, bv1, bv1};
            acc[m][0] = c0; acc[m][1] = c1;
        }
        #pragma unroll
        for (int ks = 0; ks < 4; ks++) {
            const int k0 = ks * 32 + lk;
            bf16x8 wb0 = *(const bf16x8*)&W2t[(n0 + lr) * 128 + k0];
            bf16x8 wb1 = *(const bf16x8*)&W2t[(n0 + 16 + lr) * 128 + k0];
            #pragma unroll
            for (int m = 0; m < 4; m++) {
                bf16x8 af = *(const bf16x8*)&shB[(m * 16 + lr) * LDA + k0];
                acc[m][0] = __builtin_amdgcn_mfma_f32_16x16x32_bf16(af, wb0, acc[m][0], 0, 0, 0);
                acc[m][1] = __builtin_amdgcn_mfma_f32_16x16x32_bf16(af, wb1, acc[m][1], 0, 0, 0);
            }
        }
    }
    float s0 = gamma[n0 + lr]      * (1.0f / sqrtf(var[n0 + lr] + 1e-5f));
    float t0 = beta[n0 + lr]       - mean[n0 + lr] * s0;
    float s1 = gamma[n0 + 16 + lr] * (1.0f / sqrtf(var[n0 + 16 + lr] + 1e-5f));
    float t1 = beta[n0 + 16 + lr]  - mean[n0 + 16 + lr] * s1;
    #pragma unroll
    for (int m = 0; m < 4; m++) {
        #pragma unroll
        for (int nt = 0; nt < 2; nt++) {
            float sc = nt ? s1 : s0, sf = nt ? t1 : t0;
            #pragma unroll
            for (int r = 0; r < 4; r++) {
                float y = fmaxf(fmaf(acc[m][nt][r], sc, sf), 0.f);
                shA[(m * 16 + lg * 4 + r) * LDA + (n0 + nt * 16 + lr)] = f2bf_rne(y);
            }
        }
    }
    __syncthreads();

    // GEMM3: z1 = h2 @ W1_1; wave owns cols [wave*16, +16)
    f32x4 a3[4];
    #pragma unroll
    for (int m = 0; m < 4; m++) {
        f32x4 z = {0.f, 0.f, 0.f, 0.f};
        a3[m] = z;
    }
    #pragma unroll
    for (int ks = 0; ks < 4; ks++) {
        const int k0 = ks * 32 + lk;
        bf16x8 wb = *(const bf16x8*)&W3t[(wave * 16 + lr) * 128 + k0];
        #pragma unroll
        for (int m = 0; m < 4; m++) {
            bf16x8 af = *(const bf16x8*)&shA[(m * 16 + lr) * LDA + k0];
            a3[m] = __builtin_amdgcn_mfma_f32_16x16x32_bf16(af, wb, a3[m], 0, 0, 0);
        }
    }
    #pragma unroll
    for (int m = 0; m < 4; m++) {
        #pragma unroll
        for (int r = 0; r < 4; r++) {
            int node = nodeBase + m * 16 + lg * 4 + r;
            if (node < NN)
                z1h[(size_t)node * 64 + wave * 16 + lr] = f2bf_rne(a3[m][r]);
        }
    }
}

// ---------- L1 GEMM chain via MFMA (MT=64, 4 waves): agg1(64,relu'd) @ W2_1+BN+relu -> @W1_2 -> z2h ----------
__global__ __launch_bounds__(256) void gemm_L1(
        const unsigned short* __restrict__ agg1h, unsigned short* __restrict__ z2h,
        const unsigned short* __restrict__ W21t,  // [64n][64k] bf16
        const unsigned short* __restrict__ W12t,  // [32n][64k] bf16
        const float* __restrict__ b2, const float* __restrict__ gamma,
        const float* __restrict__ beta, const float* __restrict__ mean,
        const float* __restrict__ var) {
    constexpr int MT = 64, LDA = 72;   // bf16; 144B row stride (2-way bank alias, free)
    __shared__ __align__(16) unsigned short shA[MT * LDA];
    __shared__ __align__(16) unsigned short shB[MT * LDA];
    const int tid = threadIdx.x;
    const int wave = tid >> 6, lane = tid & 63;
    const int nodeBase = blockIdx.x * MT;
    const int lr = lane & 15;
    const int lg = lane >> 4;
    const int lk = lg * 8;
    const int n0 = wave * 16;       // GEMM_A output-column base

    // stage agg1 tile (bias+relu already applied by gather_L1)
    #pragma unroll
    for (int j = 0; j < 2; j++) {
        int f = tid + j * 256;              // 512 uint4 (8 per row)
        int row = f >> 3, c = f & 7;
        int node = nodeBase + row;
        uint4 v = (node < NN) ? ((const uint4*)agg1h)[(size_t)node * 8 + c]
                              : make_uint4(0u, 0u, 0u, 0u);
        *(uint4*)&shA[row * LDA + c * 8] = v;
    }
    __syncthreads();

    // GEMM_A: h2 = relu(BN(A @ W2_1 + b2)); wave owns cols [n0, n0+16)
    f32x4 acc[4];
    {
        float bv = b2[n0 + lr];
        #pragma unroll
        for (int m = 0; m < 4; m++) {
            f32x4 c0 = {bv, bv, bv, bv};
            acc[m] = c0;
        }
        #pragma unroll
        for (int ks = 0; ks < 2; ks++) {
            const int k0 = ks * 32 + lk;
            bf16x8 wb = *(const bf16x8*)&W21t[(n0 + lr) * 64 + k0];
            #pragma unroll
            for (int m = 0; m < 4; m++) {
                bf16x8 af = *(const bf16x8*)&shA[(m * 16 + lr) * LDA + k0];
                acc[m] = __builtin_amdgcn_mfma_f32_16x16x32_bf16(af, wb, acc[m], 0, 0, 0);
            }
        }
    }
    float sc = gamma[n0 + lr] * (1.0f / sqrtf(var[n0 + lr] + 1e-5f));
    float sf = beta[n0 + lr] - mean[n0 + lr] * sc;
    #pragma unroll
    for (int m = 0; m < 4; m++) {
        #pragma unroll
        for (int r = 0; r < 4; r++) {
            float y = fmaxf(fmaf(acc[m][r], sc, sf), 0.f);
            shB[(m * 16 + lg * 4 + r) * LDA + (n0 + lr)] = f2bf_rne(y);
        }
    }
    __syncthreads();

    // GEMM_B: z2 = h2 @ W1_2 (64->32). wave: rows [(w>>1)*32,+32), cols [(w&1)*16,+16)
    const int rh = (wave >> 1) * 32, ch = (wave & 1) * 16;
    f32x4 a3[2];
    {
        f32x4 z = {0.f, 0.f, 0.f, 0.f};
        a3[0] = z; a3[1] = z;
    }
    #pragma unroll
    for (int ks = 0; ks < 2; ks++) {
        const int k0 = ks * 32 + lk;
        bf16x8 wb = *(const bf16x8*)&W12t[(ch + lr) * 64 + k0];
        #pragma unroll
        for (int m = 0; m < 2; m++) {
            bf16x8 af = *(const bf16x8*)&shB[(rh + m * 16 + lr) * LDA + k0];
            a3[m] = __builtin_amdgcn_mfma_f32_16x16x32_bf16(af, wb, a3[m], 0, 0, 0);
        }
    }
    #pragma unroll
    for (int m = 0; m < 2; m++) {
        #pragma unroll
        for (int r = 0; r < 4; r++) {
            int node = nodeBase + rh + m * 16 + lg * 4 + r;
            if (node < NN)
                z2h[(size_t)node * 32 + ch + lr] = f2bf_rne(a3[m][r]);
        }
    }
}

// ---------- L2 GEMM (MT=32): agg2(32,relu'd) @ W2_2 + BN -> dot W_lin -> logits ----------
__global__ __launch_bounds__(256) void gemm_L2(
        const unsigned short* __restrict__ agg2h, float* __restrict__ logits,
        const float* __restrict__ W2, const float* __restrict__ b2,
        const float* __restrict__ gamma, const float* __restrict__ beta,
        const float* __restrict__ mean, const float* __restrict__ var,
        const float* __restrict__ Wl, const float* __restrict__ bl) {
    constexpr int MT = 32, LD = 36;
    __shared__ float sh[MT * LD];
    const int tid = threadIdx.x;
    const int nodeBase = blockIdx.x * MT;

    // stage: 32 nodes x 32 bf16; one uint2 (4 bf16) per thread
    {
        int row = tid >> 3, c = tid & 7;
        int node = nodeBase + row;
        uint2 v = (node < NN) ? ((const uint2*)agg2h)[(size_t)node * 8 + c]
                              : make_uint2(0u, 0u);
        sh[row * LD + c * 4 + 0] = BF2F_LO(v.x);
        sh[row * LD + c * 4 + 1] = BF2F_HI(v.x);
        sh[row * LD + c * 4 + 2] = BF2F_LO(v.y);
        sh[row * LD + c * 4 + 3] = BF2F_HI(v.y);
    }
    __syncthreads();

    // GEMM: 32->32 (W2_2) + BN (no relu), dot W_lin. CT=8, RT=32
    const int colid = tid % 8, rowid = tid / 8;
    const int c0 = colid * 4, r0 = rowid;
    float acc[4];
    {
        float4 bv = *(const float4*)&b2[c0];
        acc[0] = bv.x; acc[1] = bv.y; acc[2] = bv.z; acc[3] = bv.w;
        #pragma unroll
        for (int k4 = 0; k4 < 8; k4++) {
            float4 w[4];
            #pragma unroll
            for (int kk = 0; kk < 4; kk++)
                w[kk] = *(const float4*)&W2[(k4 * 4 + kk) * 32 + c0];
            float4 a = *(const float4*)&sh[r0 * LD + k4 * 4];
            const float av[4] = {a.x, a.y, a.z, a.w};
            #pragma unroll
            for (int kk = 0; kk < 4; kk++) {
                const float* wp = (const float*)&w[kk];
                #pragma unroll
                for (int j = 0; j < 4; j++)
                    acc[j] = fmaf(av[kk], wp[j], acc[j]);
            }
        }
    }
    float4 gv = *(const float4*)&gamma[c0];
    float4 bev = *(const float4*)&beta[c0];
    float4 mv = *(const float4*)&mean[c0];
    float4 vv = *(const float4*)&var[c0];
    float4 wl = *(const float4*)&Wl[c0];
    float p = 0.f;
    {
        const float* gp = (const float*)&gv; const float* bp = (const float*)&bev;
        const float* mp = (const float*)&mv; const float* vp = (const float*)&vv;
        const float* wp = (const float*)&wl;
        #pragma unroll
        for (int j = 0; j < 4; j++) {
            float sc = gp[j] * (1.0f / sqrtf(vp[j] + 1e-5f));
            float y = (acc[j] - mp[j]) * sc + bp[j];
            p = fmaf(y, wp[j], p);
        }
    }
    p += __shfl_xor(p, 1);
    p += __shfl_xor(p, 2);
    p += __shfl_xor(p, 4);
    int node = nodeBase + r0;
    if ((tid & 7) == 0 && node < NN)
        logits[node] = (p + bl[0]) * 0.2f;
}

// ---------- head ----------
__global__ __launch_bounds__(256) void seg_softmax(
        const float* __restrict__ logits, const int* __restrict__ gstart,
        float* __restrict__ out) {
    __shared__ float slog[1024];
    __shared__ float sred[4];
    __shared__ float sbc[2];
    int g = blockIdx.x;
    int beg = gstart[g], end = gstart[g + 1];
    int cnt = end - beg;
    int t = threadIdx.x;
    if (cnt <= 0) return;
    bool fits = (cnt <= 1024);

    float lmax = -3.402823466e+38f;
    for (int i = t; i < cnt; i += 256) {
        float lg = logits[beg + i];
        if (fits) slog[i] = lg;
        lmax = fmaxf(lmax, lg);
    }
    #pragma unroll
    for (int off = 32; off > 0; off >>= 1)
        lmax = fmaxf(lmax, __shfl_down(lmax, off));
    if ((t & 63) == 0) sred[t >> 6] = lmax;
    __syncthreads();
    if (t == 0) sbc[0] = fmaxf(fmaxf(sred[0], sred[1]), fmaxf(sred[2], sred[3]));
    __syncthreads();
    float gm = sbc[0];

    float lsum = 0.f;
    for (int i = t; i < cnt; i += 256) {
        float lg = fits ? slog[i] : logits[beg + i];
        float e = expf(lg - gm);
        if (fits) slog[i] = e;
        lsum += e;
    }
    #pragma unroll
    for (int off = 32; off > 0; off >>= 1)
        lsum += __shfl_down(lsum, off);
    __syncthreads();
    if ((t & 63) == 0) sred[t >> 6] = lsum;
    __syncthreads();
    if (t == 0) sbc[1] = (sred[0] + sred[1]) + (sred[2] + sred[3]);
    __syncthreads();
    float inv = 1.0f / sbc[1];

    for (int i = t; i < cnt; i += 256) {
        float e = fits ? slog[i] : expf(logits[beg + i] - gm);
        out[beg + i] = e * inv;
    }
}

// ---------- launch ----------
extern "C" void kernel_launch(void* const* d_in, const int* in_sizes, int n_in,
                              void* d_out, int out_size, void* d_ws, size_t ws_size,
                              hipStream_t stream) {
    const float* x    = (const float*)d_in[0];
    const int*   ei   = (const int*)d_in[1];
    const int*   srcI = ei;
    const int*   dstI = ei + NE;
    const int*   batch = (const int*)d_in[2];

    const float* P[29];
    for (int i = 0; i < 29; i++) P[i] = (const float*)d_in[i];
    const float* Wlin = P[27];
    const float* blin = P[28];

    unsigned short* xh  = (unsigned short*)d_ws;       // N x 128 bf16
    unsigned short* z1h = xh + (size_t)NN * 128;       // N x 64 bf16
    unsigned short* z2h = z1h + (size_t)NN * 64;       // N x 32 bf16
    float* logits = (float*)(z2h + (size_t)NN * 32);   // N
    int* gstart = (int*)(logits + NN);                 // NG+1
    int* deg    = gstart + NG + 1;                     // N
    int* iscan  = deg + NN;                            // N
    int* rowptr = iscan + NN;                          // N+1
    int* bsum   = rowptr + NN + 1;                     // NB
    int* boff   = bsum + NB;                           // NB
    int* eoff   = boff + NB;                           // E
    int* esrc   = eoff + NE;                           // E
    uintptr_t pal = ((uintptr_t)(esrc + NE) + 255) & ~(uintptr_t)255;
    unsigned short* aggh  = (unsigned short*)pal;      // N x 128 bf16
    unsigned short* W1t   = aggh + (size_t)NN * 128;   // 128x128 bf16 [n][k]
    unsigned short* W2t   = W1t + 16384;               // 128x128 bf16 [n][k]
    unsigned short* W3t   = W2t + 16384;               // 64x128 bf16 [n][k]
    unsigned short* W21t  = W3t + 8192;                // 64x64 bf16 [n][k]
    unsigned short* W12t  = W21t + 4096;               // 32x64 bf16 [n][k]
    unsigned short* agg1h = W12t + 2048;               // N x 64 bf16
    unsigned short* agg2h = agg1h + (size_t)NN * 64;   // N x 32 bf16
    float* outp = (float*)d_out;

    const int TB = 256;

    // merged convert + CSR histogram (grid covers N4 > NE)
    hipMemsetAsync(deg, 0, NN * sizeof(int), stream);
    conv_hist<<<(N4 + TB - 1) / TB, TB, 0, stream>>>(
        (const float4*)x, (ushort4*)xh, dstI, deg, eoff);

    block_scan<<<NB, 256, 0, stream>>>(deg, iscan, bsum,
        P[3], P[5], P[11], P[13], P[19], W1t, W2t, W3t, W21t, W12t);
    scan_bsum<<<1, 256, 0, stream>>>(bsum, boff);
    finalize_bounds<<<NB, 256, 0, stream>>>(deg, iscan, boff, rowptr, batch, gstart);
    fill_csr2<<<(NE + TB - 1) / TB, TB, 0, stream>>>(srcI, dstI, rowptr, eoff, esrc);

    const int GB   = (NN + 3) / 4;     // gathers: 1 wave/node
    const int FB64 = (NN + 63) / 64;
    const int FB32 = (NN + 31) / 32;

    gather_L0<<<GB, 256, 0, stream>>>(xh, esrc, rowptr, aggh);
    gemm_L0<<<FB64, 256, 0, stream>>>(aggh, z1h, W1t, W2t, W3t,
        P[4], P[6], P[7], P[8], P[9], P[10]);
    gather_L1<<<GB, 256, 0, stream>>>(z1h, esrc, rowptr, P[12], agg1h);
    gemm_L1<<<FB64, 256, 0, stream>>>(agg1h, z2h, W21t, W12t,
        P[14], P[15], P[16], P[17], P[18]);
    gather_L2<<<GB, 256, 0, stream>>>(z2h, esrc, rowptr, P[20], agg2h);
    gemm_L2<<<FB32, 256, 0, stream>>>(agg2h, logits,
        P[21], P[22], P[23], P[24], P[25], P[26], Wlin, blin);

    seg_softmax<<<NG, 256, 0, stream>>>(logits, gstart, outp);
}

// Round 5
// 281.440 us; speedup vs baseline: 1.3146x; 1.0148x over previous
//
#include <hip/hip_runtime.h>

#define NN 50000
#define NE 800000
#define NG 256
#define NB ((NN + 255) / 256)   // scan blocks
#define N4 (NN * 128 / 4)       // float4 count of x (1.6M)
#define NQ (NE / 4)             // edge quads (200000)

typedef __attribute__((ext_vector_type(8))) short bf16x8;
typedef __attribute__((ext_vector_type(4))) float f32x4;

// ---------- bf16 helpers ----------
__device__ __forceinline__ unsigned short f2bf_rne(float f) {
    unsigned u = __float_as_uint(f);
    u += 0x7fffu + ((u >> 16) & 1u);   // round-to-nearest-even
    return (unsigned short)(u >> 16);
}
#define BF2F_LO(u) __uint_as_float((u) << 16)
#define BF2F_HI(u) __uint_as_float((u) & 0xffff0000u)

// ---------- merged: x->bf16 convert + degree histogram (deg pre-zeroed) ----------
// Edge histogram: 32 quads per block on lanes 0-31 of wave 0 (4 independent
// returning atomics per lane -> 4-deep atomic MLP, evenly spread over all CUs).
__global__ void conv_hist(const float4* __restrict__ x, ushort4* __restrict__ xh,
                          const int4* __restrict__ dst4, int* __restrict__ deg,
                          int4* __restrict__ eoff4) {
    int i = blockIdx.x * 256 + threadIdx.x;
    if (i < N4) {
        float4 v = x[i];
        ushort4 o;
        o.x = f2bf_rne(v.x); o.y = f2bf_rne(v.y);
        o.z = f2bf_rne(v.z); o.w = f2bf_rne(v.w);
        xh[i] = o;
    }
    int t = threadIdx.x;
    if (t < 32) {
        int q = blockIdx.x * 32 + t;        // 6250 blocks * 32 = NQ exactly
        if (q < NQ) {
            int4 d = dst4[q];
            int o0 = atomicAdd(&deg[d.x], 1);
            int o1 = atomicAdd(&deg[d.y], 1);
            int o2 = atomicAdd(&deg[d.z], 1);
            int o3 = atomicAdd(&deg[d.w], 1);
            eoff4[q] = make_int4(o0, o1, o2, o3);
        }
    }
}

// ---------- CSR scan (+ weight transpose/convert for MFMA gemms) ----------
__global__ void block_scan(const int* __restrict__ deg, int* __restrict__ iscan,
                           int* __restrict__ bsum,
                           const float* __restrict__ W1, const float* __restrict__ W2,
                           const float* __restrict__ W3,
                           const float* __restrict__ W21, const float* __restrict__ W12,
                           unsigned short* __restrict__ W1t,
                           unsigned short* __restrict__ W2t,
                           unsigned short* __restrict__ W3t,
                           unsigned short* __restrict__ W21t,
                           unsigned short* __restrict__ W12t) {
    // weight prep: Wt[n][k] = bf16(W[k][n]) (independent side-work)
    int gidx = blockIdx.x * 256 + threadIdx.x;
    if (gidx < 16384) {
        int n = gidx >> 7, k = gidx & 127;
        W1t[gidx] = f2bf_rne(W1[k * 128 + n]);
        W2t[gidx] = f2bf_rne(W2[k * 128 + n]);
    } else if (gidx < 24576) {
        int i2 = gidx - 16384;
        int n = i2 >> 7, k = i2 & 127;      // n in [0,64), k in [0,128)
        W3t[i2] = f2bf_rne(W3[k * 64 + n]);
    } else if (gidx < 28672) {
        int i3 = gidx - 24576;
        int n = i3 >> 6, k = i3 & 63;       // 64x64
        W21t[i3] = f2bf_rne(W21[k * 64 + n]);
    } else if (gidx < 30720) {
        int i4 = gidx - 28672;
        int n = i4 >> 6, k = i4 & 63;       // n in [0,32), k in [0,64)
        W12t[i4] = f2bf_rne(W12[k * 32 + n]);
    }

    __shared__ int sh[256];
    int t = threadIdx.x;
    int i = blockIdx.x * 256 + t;
    int v = (i < NN) ? deg[i] : 0;
    sh[t] = v;
    __syncthreads();
    #pragma unroll
    for (int off = 1; off < 256; off <<= 1) {
        int add = (t >= off) ? sh[t - off] : 0;
        __syncthreads();
        sh[t] += add;
        __syncthreads();
    }
    if (i < NN) iscan[i] = sh[t];
    if (t == 255) bsum[blockIdx.x] = sh[255];
}

__global__ void scan_bsum(const int* __restrict__ bsum, int* __restrict__ boff) {
    __shared__ int sh[256];
    int t = threadIdx.x;
    int v = (t < NB) ? bsum[t] : 0;
    sh[t] = v;
    __syncthreads();
    #pragma unroll
    for (int off = 1; off < 256; off <<= 1) {
        int add = (t >= off) ? sh[t - off] : 0;
        __syncthreads();
        sh[t] += add;
        __syncthreads();
    }
    if (t < NB) boff[t] = sh[t] - v;  // exclusive
}

// merged: rowptr finalize + graph-bounds (batch is sorted)
__global__ void finalize_bounds(const int* __restrict__ deg, const int* __restrict__ iscan,
                                const int* __restrict__ boff, int* __restrict__ rowptr,
                                const int* __restrict__ batch, int* __restrict__ gstart) {
    int i = blockIdx.x * 256 + threadIdx.x;
    if (i < NN) {
        rowptr[i] = iscan[i] - deg[i] + boff[blockIdx.x];
        int b = batch[i];
        if (i == 0) {
            for (int g = 0; g <= b; g++) gstart[g] = 0;
        } else {
            int p = batch[i - 1];
            for (int g = p + 1; g <= b; g++) gstart[g] = i;
        }
        if (i == NN - 1) {
            for (int g = b + 1; g <= NG; g++) gstart[g] = NN;
        }
    }
    if (i == 0) rowptr[NN] = NE;
}

// 4 edges per thread: int4 loads, 4 independent rowptr gathers + scatters
__global__ void fill_csr2(const int4* __restrict__ src4, const int4* __restrict__ dst4,
                          const int* __restrict__ rowptr, const int4* __restrict__ eoff4,
                          int* __restrict__ esrc) {
    int q = blockIdx.x * 256 + threadIdx.x;
    if (q >= NQ) return;
    int4 s = src4[q];
    int4 d = dst4[q];
    int4 o = eoff4[q];
    int r0 = rowptr[d.x];
    int r1 = rowptr[d.y];
    int r2 = rowptr[d.z];
    int r3 = rowptr[d.w];
    esrc[r0 + o.x] = s.x;
    esrc[r1 + o.y] = s.y;
    esrc[r2 + o.z] = s.z;
    esrc[r3 + o.w] = s.w;
}

// ---------- bf16 wave-cooperative gathers ----------
// C lane-chunks per row, EPI = 64/C edges per pass; 4x/2x/1x unroll keeps
// up to 4 independent loads in flight.

// 16B-lane variant (rows = 256B): x (128 cols)
template <int C4>
__device__ __forceinline__ void gather_bf16(const uint4* __restrict__ x4,
                                            const int* __restrict__ esrc,
                                            int beg, int cnt, int node, int lane,
                                            float* a /* [8] */) {
    constexpr int EPI = 64 / C4;
    const int chunk = lane & (C4 - 1);
    const int esl   = lane / C4;
    #define ACC_U4(u) do { \
        a[0] += BF2F_LO((u).x); a[1] += BF2F_HI((u).x); \
        a[2] += BF2F_LO((u).y); a[3] += BF2F_HI((u).y); \
        a[4] += BF2F_LO((u).z); a[5] += BF2F_HI((u).z); \
        a[6] += BF2F_LO((u).w); a[7] += BF2F_HI((u).w); } while (0)
    if (esl == 0) { uint4 u = x4[(size_t)node * C4 + chunk]; ACC_U4(u); }
    for (int c = 0; c < cnt; c += 64) {
        int take = min(64, cnt - c);
        int myi = (lane < take) ? esrc[beg + c + lane] : 0;
        int i = 0;
        for (; i + 4 * EPI <= take; i += 4 * EPI) {
            int s0 = __shfl(myi, i + esl);
            int s1 = __shfl(myi, i + EPI + esl);
            int s2 = __shfl(myi, i + 2 * EPI + esl);
            int s3 = __shfl(myi, i + 3 * EPI + esl);
            uint4 u0 = x4[(size_t)s0 * C4 + chunk];
            uint4 u1 = x4[(size_t)s1 * C4 + chunk];
            uint4 u2 = x4[(size_t)s2 * C4 + chunk];
            uint4 u3 = x4[(size_t)s3 * C4 + chunk];
            ACC_U4(u0); ACC_U4(u1); ACC_U4(u2); ACC_U4(u3);
        }
        if (i + 2 * EPI <= take) {
            int s0 = __shfl(myi, i + esl);
            int s1 = __shfl(myi, i + EPI + esl);
            uint4 u0 = x4[(size_t)s0 * C4 + chunk];
            uint4 u1 = x4[(size_t)s1 * C4 + chunk];
            ACC_U4(u0); ACC_U4(u1);
            i += 2 * EPI;
        }
        if (i + EPI <= take) {
            int s = __shfl(myi, i + esl);
            uint4 u = x4[(size_t)s * C4 + chunk];
            ACC_U4(u);
            i += EPI;
        }
        int rem = take - i;
        if (rem > 0) {
            int s = __shfl(myi, i + ((esl < rem) ? esl : 0));
            uint4 u = x4[(size_t)s * C4 + chunk];
            if (esl < rem) ACC_U4(u);
        }
    }
    #undef ACC_U4
    for (int off = 32; off >= C4; off >>= 1) {
        #pragma unroll
        for (int q = 0; q < 8; q++)
            a[q] += __shfl_xor(a[q], off);
    }
}

// 8B-lane variant (rows = 128B): z1 (64 cols). C=16, EPI=4.
template <int C>
__device__ __forceinline__ void gather_bf16_u2(const uint2* __restrict__ x2,
                                               const int* __restrict__ esrc,
                                               int beg, int cnt, int node, int lane,
                                               float* a /* [4] */) {
    constexpr int EPI = 64 / C;
    const int chunk = lane & (C - 1);
    const int esl   = lane / C;
    #define ACC_U2(u) do { \
        a[0] += BF2F_LO((u).x); a[1] += BF2F_HI((u).x); \
        a[2] += BF2F_LO((u).y); a[3] += BF2F_HI((u).y); } while (0)
    if (esl == 0) { uint2 u = x2[(size_t)node * C + chunk]; ACC_U2(u); }
    for (int c = 0; c < cnt; c += 64) {
        int take = min(64, cnt - c);
        int myi = (lane < take) ? esrc[beg + c + lane] : 0;
        int i = 0;
        for (; i + 4 * EPI <= take; i += 4 * EPI) {
            int s0 = __shfl(myi, i + esl);
            int s1 = __shfl(myi, i + EPI + esl);
            int s2 = __shfl(myi, i + 2 * EPI + esl);
            int s3 = __shfl(myi, i + 3 * EPI + esl);
            uint2 u0 = x2[(size_t)s0 * C + chunk];
            uint2 u1 = x2[(size_t)s1 * C + chunk];
            uint2 u2 = x2[(size_t)s2 * C + chunk];
            uint2 u3 = x2[(size_t)s3 * C + chunk];
            ACC_U2(u0); ACC_U2(u1); ACC_U2(u2); ACC_U2(u3);
        }
        if (i + 2 * EPI <= take) {
            int s0 = __shfl(myi, i + esl);
            int s1 = __shfl(myi, i + EPI + esl);
            uint2 u0 = x2[(size_t)s0 * C + chunk];
            uint2 u1 = x2[(size_t)s1 * C + chunk];
            ACC_U2(u0); ACC_U2(u1);
            i += 2 * EPI;
        }
        if (i + EPI <= take) {
            int s = __shfl(myi, i + esl);
            uint2 u = x2[(size_t)s * C + chunk];
            ACC_U2(u);
            i += EPI;
        }
        int rem = take - i;
        if (rem > 0) {
            int s = __shfl(myi, i + ((esl < rem) ? esl : 0));
            uint2 u = x2[(size_t)s * C + chunk];
            if (esl < rem) ACC_U2(u);
        }
    }
    #undef ACC_U2
    for (int off = 32; off >= C; off >>= 1) {
        #pragma unroll
        for (int q = 0; q < 4; q++)
            a[q] += __shfl_xor(a[q], off);
    }
}

// 4B-lane variant (rows = 64B): z2 (32 cols). C=16, EPI=4.
template <int C>
__device__ __forceinline__ void gather_bf16_u1(const unsigned* __restrict__ x1,
                                               const int* __restrict__ esrc,
                                               int beg, int cnt, int node, int lane,
                                               float* a /* [2] */) {
    constexpr int EPI = 64 / C;
    const int chunk = lane & (C - 1);
    const int esl   = lane / C;
    #define ACC_U1(u) do { \
        a[0] += BF2F_LO(u); a[1] += BF2F_HI(u); } while (0)
    if (esl == 0) { unsigned u = x1[(size_t)node * C + chunk]; ACC_U1(u); }
    for (int c = 0; c < cnt; c += 64) {
        int take = min(64, cnt - c);
        int myi = (lane < take) ? esrc[beg + c + lane] : 0;
        int i = 0;
        for (; i + 4 * EPI <= take; i += 4 * EPI) {
            int s0 = __shfl(myi, i + esl);
            int s1 = __shfl(myi, i + EPI + esl);
            int s2 = __shfl(myi, i + 2 * EPI + esl);
            int s3 = __shfl(myi, i + 3 * EPI + esl);
            unsigned u0 = x1[(size_t)s0 * C + chunk];
            unsigned u1 = x1[(size_t)s1 * C + chunk];
            unsigned u2 = x1[(size_t)s2 * C + chunk];
            unsigned u3 = x1[(size_t)s3 * C + chunk];
            ACC_U1(u0); ACC_U1(u1); ACC_U1(u2); ACC_U1(u3);
        }
        if (i + 2 * EPI <= take) {
            int s0 = __shfl(myi, i + esl);
            int s1 = __shfl(myi, i + EPI + esl);
            unsigned u0 = x1[(size_t)s0 * C + chunk];
            unsigned u1 = x1[(size_t)s1 * C + chunk];
            ACC_U1(u0); ACC_U1(u1);
            i += 2 * EPI;
        }
        if (i + EPI <= take) {
            int s = __shfl(myi, i + esl);
            unsigned u = x1[(size_t)s * C + chunk];
            ACC_U1(u);
            i += EPI;
        }
        int rem = take - i;
        if (rem > 0) {
            int s = __shfl(myi, i + ((esl < rem) ? esl : 0));
            unsigned u = x1[(size_t)s * C + chunk];
            if (esl < rem) ACC_U1(u);
        }
    }
    #undef ACC_U1
    for (int off = 32; off >= C; off >>= 1) {
        #pragma unroll
        for (int q = 0; q < 2; q++)
            a[q] += __shfl_xor(a[q], off);
    }
}

// ---------- L0 gather: one wave per node -> bf16 agg ----------
__global__ __launch_bounds__(256) void gather_L0(
        const unsigned short* __restrict__ xh, const int* __restrict__ esrc,
        const int* __restrict__ rowptr, unsigned short* __restrict__ aggh /* N x 128 bf16 */) {
    const int wave = threadIdx.x >> 6, lane = threadIdx.x & 63;
    const int node = blockIdx.x * 4 + wave;
    if (node >= NN) return;
    float a[8] = {0, 0, 0, 0, 0, 0, 0, 0};
    int beg = rowptr[node], end = rowptr[node + 1];
    gather_bf16<16>((const uint4*)xh, esrc, beg, end - beg, node, lane, a);
    if (lane < 16) {
        uint4 o;
        o.x = (unsigned)f2bf_rne(a[0]) | ((unsigned)f2bf_rne(a[1]) << 16);
        o.y = (unsigned)f2bf_rne(a[2]) | ((unsigned)f2bf_rne(a[3]) << 16);
        o.z = (unsigned)f2bf_rne(a[4]) | ((unsigned)f2bf_rne(a[5]) << 16);
        o.w = (unsigned)f2bf_rne(a[6]) | ((unsigned)f2bf_rne(a[7]) << 16);
        *(uint4*)&aggh[(size_t)node * 128 + lane * 8] = o;
    }
}

// ---------- L1 gather: one wave per node; +b1, relu -> bf16 agg1 ----------
__global__ __launch_bounds__(256) void gather_L1(
        const unsigned short* __restrict__ z1h, const int* __restrict__ esrc,
        const int* __restrict__ rowptr, const float* __restrict__ b1,
        unsigned short* __restrict__ agg1h /* N x 64 bf16 */) {
    const int wave = threadIdx.x >> 6, lane = threadIdx.x & 63;
    const int node = blockIdx.x * 4 + wave;
    if (node >= NN) return;
    float a[4] = {0, 0, 0, 0};
    int beg = rowptr[node], end = rowptr[node + 1];
    gather_bf16_u2<16>((const uint2*)z1h, esrc, beg, end - beg, node, lane, a);
    if (lane < 16) {
        float4 bv = *(const float4*)&b1[lane * 4];
        uint2 o;
        o.x = (unsigned)f2bf_rne(fmaxf(a[0] + bv.x, 0.f)) |
              ((unsigned)f2bf_rne(fmaxf(a[1] + bv.y, 0.f)) << 16);
        o.y = (unsigned)f2bf_rne(fmaxf(a[2] + bv.z, 0.f)) |
              ((unsigned)f2bf_rne(fmaxf(a[3] + bv.w, 0.f)) << 16);
        *(uint2*)&agg1h[(size_t)node * 64 + lane * 4] = o;
    }
}

// ---------- L2 gather: one wave per node; +b1, relu -> bf16 agg2 ----------
__global__ __launch_bounds__(256) void gather_L2(
        const unsigned short* __restrict__ z2h, const int* __restrict__ esrc,
        const int* __restrict__ rowptr, const float* __restrict__ b1,
        unsigned short* __restrict__ agg2h /* N x 32 bf16 */) {
    const int wave = threadIdx.x >> 6, lane = threadIdx.x & 63;
    const int node = blockIdx.x * 4 + wave;
    if (node >= NN) return;
    float a[2] = {0, 0};
    int beg = rowptr[node], end = rowptr[node + 1];
    gather_bf16_u1<16>((const unsigned*)z2h, esrc, beg, end - beg, node, lane, a);
    if (lane < 16) {
        float2 bv = *(const float2*)&b1[lane * 2];
        unsigned o = (unsigned)f2bf_rne(fmaxf(a[0] + bv.x, 0.f)) |
                     ((unsigned)f2bf_rne(fmaxf(a[1] + bv.y, 0.f)) << 16);
        *(unsigned*)&agg2h[(size_t)node * 32 + lane * 2] = o;
    }
}

// ---------- L0 GEMM chain via MFMA bf16 (MT=64, 4 waves) ----------
// GEMM1: relu(agg@W1+b1) -> GEMM2: BN(.@W2+b2), relu -> GEMM3: .@W1_1 -> z1h
// MFMA 16x16x32 bf16 layouts: A[m=l&15][k=(l>>4)*8+j], B[k=(l>>4)*8+j][n=l&15],
// D[row=(l>>4)*4+r][col=l&15]  (m89-verified C/D mapping)
__global__ __launch_bounds__(256) void gemm_L0(
        const unsigned short* __restrict__ aggh, unsigned short* __restrict__ z1h,
        const unsigned short* __restrict__ W1t,  // [128n][128k] bf16
        const unsigned short* __restrict__ W2t,  // [128n][128k] bf16
        const unsigned short* __restrict__ W3t,  // [64n][128k] bf16
        const float* __restrict__ b1, const float* __restrict__ b2,
        const float* __restrict__ gamma, const float* __restrict__ beta,
        const float* __restrict__ mean, const float* __restrict__ var) {
    constexpr int MT = 64, LDA = 136;   // bf16 units; 272B row stride
    __shared__ __align__(16) unsigned short shA[MT * LDA];
    __shared__ __align__(16) unsigned short shB[MT * LDA];
    const int tid = threadIdx.x;
    const int wave = tid >> 6, lane = tid & 63;
    const int nodeBase = blockIdx.x * MT;
    const int lr = lane & 15;
    const int lg = lane >> 4;
    const int lk = lg * 8;
    const int n0 = wave * 32;

    // stage bf16 agg tile -> shA, coalesced 16B
    #pragma unroll
    for (int j = 0; j < 4; j++) {
        int f = tid + j * 256;
        int row = f >> 4, c = f & 15;
        int node = nodeBase + row;
        uint4 v = (node < NN) ? ((const uint4*)aggh)[(size_t)node * 16 + c]
                              : make_uint4(0u, 0u, 0u, 0u);
        *(uint4*)&shA[row * LDA + c * 8] = v;
    }
    __syncthreads();

    f32x4 acc[4][2];

    // GEMM1: h1 = relu(A @ W1 + b1); wave owns cols [n0, n0+32)
    {
        float bv0 = b1[n0 + lr], bv1 = b1[n0 + 16 + lr];
        #pragma unroll
        for (int m = 0; m < 4; m++) {
            f32x4 c0 = {bv0, bv0, bv0, bv0};
            f32x4 c1 = {bv1, bv1, bv1, bv1};
            acc[m][0] = c0; acc[m][1] = c1;
        }
        #pragma unroll
        for (int ks = 0; ks < 4; ks++) {
            const int k0 = ks * 32 + lk;
            bf16x8 wb0 = *(const bf16x8*)&W1t[(n0 + lr) * 128 + k0];
            bf16x8 wb1 = *(const bf16x8*)&W1t[(n0 + 16 + lr) * 128 + k0];
            #pragma unroll
            for (int m = 0; m < 4; m++) {
                bf16x8 af = *(const bf16x8*)&shA[(m * 16 + lr) * LDA + k0];
                acc[m][0] = __builtin_amdgcn_mfma_f32_16x16x32_bf16(af, wb0, acc[m][0], 0, 0, 0);
                acc[m][1] = __builtin_amdgcn_mfma_f32_16x16x32_bf16(af, wb1, acc[m][1], 0, 0, 0);
            }
        }
    }
    #pragma unroll
    for (int m = 0; m < 4; m++) {
        #pragma unroll
        for (int nt = 0; nt < 2; nt++) {
            #pragma unroll
            for (int r = 0; r < 4; r++) {
                shB[(m * 16 + lg * 4 + r) * LDA + (n0 + nt * 16 + lr)] =
                    f2bf_rne(fmaxf(acc[m][nt][r], 0.f));
            }
        }
    }
    __syncthreads();

    // GEMM2: h2 = relu(BN(h1 @ W2 + b2))
    {
        float bv0 = b2[n0 + lr], bv1 = b2[n0 + 16 + lr];
        #pragma unroll
        for (int m = 0; m < 4; m++) {
            f32x4 c0 = {bv0, bv0, bv0, bv0};
            f32x4 c1 = {bv1, bv1, bv1, bv1};
            acc[m][0] = c0; acc[m][1] = c1;
        }
        #pragma unroll
        for (int ks = 0; ks < 4; ks++) {
            const int k0 = ks * 32 + lk;
            bf16x8 wb0 = *(const bf16x8*)&W2t[(n0 + lr) * 128 + k0];
            bf16x8 wb1 = *(const bf16x8*)&W2t[(n0 + 16 + lr) * 128 + k0];
            #pragma unroll
            for (int m = 0; m < 4; m++) {
                bf16x8 af = *(const bf16x8*)&shB[(m * 16 + lr) * LDA + k0];
                acc[m][0] = __builtin_amdgcn_mfma_f32_16x16x32_bf16(af, wb0, acc[m][0], 0, 0, 0);
                acc[m][1] = __builtin_amdgcn_mfma_f32_16x16x32_bf16(af, wb1, acc[m][1], 0, 0, 0);
            }
        }
    }
    float s0 = gamma[n0 + lr]      * (1.0f / sqrtf(var[n0 + lr] + 1e-5f));
    float t0 = beta[n0 + lr]       - mean[n0 + lr] * s0;
    float s1 = gamma[n0 + 16 + lr] * (1.0f / sqrtf(var[n0 + 16 + lr] + 1e-5f));
    float t1 = beta[n0 + 16 + lr]  - mean[n0 + 16 + lr] * s1;
    #pragma unroll
    for (int m = 0; m < 4; m++) {
        #pragma unroll
        for (int nt = 0; nt < 2; nt++) {
            float sc = nt ? s1 : s0, sf = nt ? t1 : t0;
            #pragma unroll
            for (int r = 0; r < 4; r++) {
                float y = fmaxf(fmaf(acc[m][nt][r], sc, sf), 0.f);
                shA[(m * 16 + lg * 4 + r) * LDA + (n0 + nt * 16 + lr)] = f2bf_rne(y);
            }
        }
    }
    __syncthreads();

    // GEMM3: z1 = h2 @ W1_1; wave owns cols [wave*16, +16)
    f32x4 a3[4];
    #pragma unroll
    for (int m = 0; m < 4; m++) {
        f32x4 z = {0.f, 0.f, 0.f, 0.f};
        a3[m] = z;
    }
    #pragma unroll
    for (int ks = 0; ks < 4; ks++) {
        const int k0 = ks * 32 + lk;
        bf16x8 wb = *(const bf16x8*)&W3t[(wave * 16 + lr) * 128 + k0];
        #pragma unroll
        for (int m = 0; m < 4; m++) {
            bf16x8 af = *(const bf16x8*)&shA[(m * 16 + lr) * LDA + k0];
            a3[m] = __builtin_amdgcn_mfma_f32_16x16x32_bf16(af, wb, a3[m], 0, 0, 0);
        }
    }
    #pragma unroll
    for (int m = 0; m < 4; m++) {
        #pragma unroll
        for (int r = 0; r < 4; r++) {
            int node = nodeBase + m * 16 + lg * 4 + r;
            if (node < NN)
                z1h[(size_t)node * 64 + wave * 16 + lr] = f2bf_rne(a3[m][r]);
        }
    }
}

// ---------- L1 GEMM chain via MFMA (MT=64, 4 waves): agg1(64,relu'd) @ W2_1+BN+relu -> @W1_2 -> z2h ----------
__global__ __launch_bounds__(256) void gemm_L1(
        const unsigned short* __restrict__ agg1h, unsigned short* __restrict__ z2h,
        const unsigned short* __restrict__ W21t,  // [64n][64k] bf16
        const unsigned short* __restrict__ W12t,  // [32n][64k] bf16
        const float* __restrict__ b2, const float* __restrict__ gamma,
        const float* __restrict__ beta, const float* __restrict__ mean,
        const float* __restrict__ var) {
    constexpr int MT = 64, LDA = 72;   // bf16; 144B row stride (2-way bank alias, free)
    __shared__ __align__(16) unsigned short shA[MT * LDA];
    __shared__ __align__(16) unsigned short shB[MT * LDA];
    const int tid = threadIdx.x;
    const int wave = tid >> 6, lane = tid & 63;
    const int nodeBase = blockIdx.x * MT;
    const int lr = lane & 15;
    const int lg = lane >> 4;
    const int lk = lg * 8;
    const int n0 = wave * 16;       // GEMM_A output-column base

    // stage agg1 tile (bias+relu already applied by gather_L1)
    #pragma unroll
    for (int j = 0; j < 2; j++) {
        int f = tid + j * 256;              // 512 uint4 (8 per row)
        int row = f >> 3, c = f & 7;
        int node = nodeBase + row;
        uint4 v = (node < NN) ? ((const uint4*)agg1h)[(size_t)node * 8 + c]
                              : make_uint4(0u, 0u, 0u, 0u);
        *(uint4*)&shA[row * LDA + c * 8] = v;
    }
    __syncthreads();

    // GEMM_A: h2 = relu(BN(A @ W2_1 + b2)); wave owns cols [n0, n0+16)
    f32x4 acc[4];
    {
        float bv = b2[n0 + lr];
        #pragma unroll
        for (int m = 0; m < 4; m++) {
            f32x4 c0 = {bv, bv, bv, bv};
            acc[m] = c0;
        }
        #pragma unroll
        for (int ks = 0; ks < 2; ks++) {
            const int k0 = ks * 32 + lk;
            bf16x8 wb = *(const bf16x8*)&W21t[(n0 + lr) * 64 + k0];
            #pragma unroll
            for (int m = 0; m < 4; m++) {
                bf16x8 af = *(const bf16x8*)&shA[(m * 16 + lr) * LDA + k0];
                acc[m] = __builtin_amdgcn_mfma_f32_16x16x32_bf16(af, wb, acc[m], 0, 0, 0);
            }
        }
    }
    float sc = gamma[n0 + lr] * (1.0f / sqrtf(var[n0 + lr] + 1e-5f));
    float sf = beta[n0 + lr] - mean[n0 + lr] * sc;
    #pragma unroll
    for (int m = 0; m < 4; m++) {
        #pragma unroll
        for (int r = 0; r < 4; r++) {
            float y = fmaxf(fmaf(acc[m][r], sc, sf), 0.f);
            shB[(m * 16 + lg * 4 + r) * LDA + (n0 + lr)] = f2bf_rne(y);
        }
    }
    __syncthreads();

    // GEMM_B: z2 = h2 @ W1_2 (64->32). wave: rows [(w>>1)*32,+32), cols [(w&1)*16,+16)
    const int rh = (wave >> 1) * 32, ch = (wave & 1) * 16;
    f32x4 a3[2];
    {
        f32x4 z = {0.f, 0.f, 0.f, 0.f};
        a3[0] = z; a3[1] = z;
    }
    #pragma unroll
    for (int ks = 0; ks < 2; ks++) {
        const int k0 = ks * 32 + lk;
        bf16x8 wb = *(const bf16x8*)&W12t[(ch + lr) * 64 + k0];
        #pragma unroll
        for (int m = 0; m < 2; m++) {
            bf16x8 af = *(const bf16x8*)&shB[(rh + m * 16 + lr) * LDA + k0];
            a3[m] = __builtin_amdgcn_mfma_f32_16x16x32_bf16(af, wb, a3[m], 0, 0, 0);
        }
    }
    #pragma unroll
    for (int m = 0; m < 2; m++) {
        #pragma unroll
        for (int r = 0; r < 4; r++) {
            int node = nodeBase + rh + m * 16 + lg * 4 + r;
            if (node < NN)
                z2h[(size_t)node * 32 + ch + lr] = f2bf_rne(a3[m][r]);
        }
    }
}

// ---------- L2 GEMM (MT=32): agg2(32,relu'd) @ W2_2 + BN -> dot W_lin -> logits ----------
__global__ __launch_bounds__(256) void gemm_L2(
        const unsigned short* __restrict__ agg2h, float* __restrict__ logits,
        const float* __restrict__ W2, const float* __restrict__ b2,
        const float* __restrict__ gamma, const float* __restrict__ beta,
        const float* __restrict__ mean, const float* __restrict__ var,
        const float* __restrict__ Wl, const float* __restrict__ bl) {
    constexpr int MT = 32, LD = 36;
    __shared__ float sh[MT * LD];
    const int tid = threadIdx.x;
    const int nodeBase = blockIdx.x * MT;

    // stage: 32 nodes x 32 bf16; one uint2 (4 bf16) per thread
    {
        int row = tid >> 3, c = tid & 7;
        int node = nodeBase + row;
        uint2 v = (node < NN) ? ((const uint2*)agg2h)[(size_t)node * 8 + c]
                              : make_uint2(0u, 0u);
        sh[row * LD + c * 4 + 0] = BF2F_LO(v.x);
        sh[row * LD + c * 4 + 1] = BF2F_HI(v.x);
        sh[row * LD + c * 4 + 2] = BF2F_LO(v.y);
        sh[row * LD + c * 4 + 3] = BF2F_HI(v.y);
    }
    __syncthreads();

    // GEMM: 32->32 (W2_2) + BN (no relu), dot W_lin. CT=8, RT=32
    const int colid = tid % 8, rowid = tid / 8;
    const int c0 = colid * 4, r0 = rowid;
    float acc[4];
    {
        float4 bv = *(const float4*)&b2[c0];
        acc[0] = bv.x; acc[1] = bv.y; acc[2] = bv.z; acc[3] = bv.w;
        #pragma unroll
        for (int k4 = 0; k4 < 8; k4++) {
            float4 w[4];
            #pragma unroll
            for (int kk = 0; kk < 4; kk++)
                w[kk] = *(const float4*)&W2[(k4 * 4 + kk) * 32 + c0];
            float4 a = *(const float4*)&sh[r0 * LD + k4 * 4];
            const float av[4] = {a.x, a.y, a.z, a.w};
            #pragma unroll
            for (int kk = 0; kk < 4; kk++) {
                const float* wp = (const float*)&w[kk];
                #pragma unroll
                for (int j = 0; j < 4; j++)
                    acc[j] = fmaf(av[kk], wp[j], acc[j]);
            }
        }
    }
    float4 gv = *(const float4*)&gamma[c0];
    float4 bev = *(const float4*)&beta[c0];
    float4 mv = *(const float4*)&mean[c0];
    float4 vv = *(const float4*)&var[c0];
    float4 wl = *(const float4*)&Wl[c0];
    float p = 0.f;
    {
        const float* gp = (const float*)&gv; const float* bp = (const float*)&bev;
        const float* mp = (const float*)&mv; const float* vp = (const float*)&vv;
        const float* wp = (const float*)&wl;
        #pragma unroll
        for (int j = 0; j < 4; j++) {
            float sc = gp[j] * (1.0f / sqrtf(vp[j] + 1e-5f));
            float y = (acc[j] - mp[j]) * sc + bp[j];
            p = fmaf(y, wp[j], p);
        }
    }
    p += __shfl_xor(p, 1);
    p += __shfl_xor(p, 2);
    p += __shfl_xor(p, 4);
    int node = nodeBase + r0;
    if ((tid & 7) == 0 && node < NN)
        logits[node] = (p + bl[0]) * 0.2f;
}

// ---------- head ----------
__global__ __launch_bounds__(256) void seg_softmax(
        const float* __restrict__ logits, const int* __restrict__ gstart,
        float* __restrict__ out) {
    __shared__ float slog[1024];
    __shared__ float sred[4];
    __shared__ float sbc[2];
    int g = blockIdx.x;
    int beg = gstart[g], end = gstart[g + 1];
    int cnt = end - beg;
    int t = threadIdx.x;
    if (cnt <= 0) return;
    bool fits = (cnt <= 1024);

    float lmax = -3.402823466e+38f;
    for (int i = t; i < cnt; i += 256) {
        float lg = logits[beg + i];
        if (fits) slog[i] = lg;
        lmax = fmaxf(lmax, lg);
    }
    #pragma unroll
    for (int off = 32; off > 0; off >>= 1)
        lmax = fmaxf(lmax, __shfl_down(lmax, off));
    if ((t & 63) == 0) sred[t >> 6] = lmax;
    __syncthreads();
    if (t == 0) sbc[0] = fmaxf(fmaxf(sred[0], sred[1]), fmaxf(sred[2], sred[3]));
    __syncthreads();
    float gm = sbc[0];

    float lsum = 0.f;
    for (int i = t; i < cnt; i += 256) {
        float lg = fits ? slog[i] : logits[beg + i];
        float e = expf(lg - gm);
        if (fits) slog[i] = e;
        lsum += e;
    }
    #pragma unroll
    for (int off = 32; off > 0; off >>= 1)
        lsum += __shfl_down(lsum, off);
    __syncthreads();
    if ((t & 63) == 0) sred[t >> 6] = lsum;
    __syncthreads();
    if (t == 0) sbc[1] = (sred[0] + sred[1]) + (sred[2] + sred[3]);
    __syncthreads();
    float inv = 1.0f / sbc[1];

    for (int i = t; i < cnt; i += 256) {
        float e = fits ? slog[i] : expf(logits[beg + i] - gm);
        out[beg + i] = e * inv;
    }
}

// ---------- launch ----------
extern "C" void kernel_launch(void* const* d_in, const int* in_sizes, int n_in,
                              void* d_out, int out_size, void* d_ws, size_t ws_size,
                              hipStream_t stream) {
    const float* x    = (const float*)d_in[0];
    const int*   ei   = (const int*)d_in[1];
    const int*   srcI = ei;
    const int*   dstI = ei + NE;
    const int*   batch = (const int*)d_in[2];

    const float* P[29];
    for (int i = 0; i < 29; i++) P[i] = (const float*)d_in[i];
    const float* Wlin = P[27];
    const float* blin = P[28];

    unsigned short* xh  = (unsigned short*)d_ws;       // N x 128 bf16
    unsigned short* z1h = xh + (size_t)NN * 128;       // N x 64 bf16
    unsigned short* z2h = z1h + (size_t)NN * 64;       // N x 32 bf16
    float* logits = (float*)(z2h + (size_t)NN * 32);   // N
    int* gstart = (int*)(logits + NN);                 // NG+1
    int* deg    = gstart + NG + 1;                     // N
    int* iscan  = deg + NN;                            // N
    int* rowptr = iscan + NN;                          // N+1
    int* bsum   = rowptr + NN + 1;                     // NB
    int* boff   = bsum + NB;                           // NB
    uintptr_t eal = ((uintptr_t)(boff + NB) + 15) & ~(uintptr_t)15;
    int* eoff   = (int*)eal;                           // E (16B aligned)
    int* esrc   = eoff + NE;                           // E
    uintptr_t pal = ((uintptr_t)(esrc + NE) + 255) & ~(uintptr_t)255;
    unsigned short* aggh  = (unsigned short*)pal;      // N x 128 bf16
    unsigned short* W1t   = aggh + (size_t)NN * 128;   // 128x128 bf16 [n][k]
    unsigned short* W2t   = W1t + 16384;               // 128x128 bf16 [n][k]
    unsigned short* W3t   = W2t + 16384;               // 64x128 bf16 [n][k]
    unsigned short* W21t  = W3t + 8192;                // 64x64 bf16 [n][k]
    unsigned short* W12t  = W21t + 4096;               // 32x64 bf16 [n][k]
    unsigned short* agg1h = W12t + 2048;               // N x 64 bf16
    unsigned short* agg2h = agg1h + (size_t)NN * 64;   // N x 32 bf16
    float* outp = (float*)d_out;

    const int TB = 256;

    // merged convert + CSR histogram (6250 blocks; 32 edge-quads per block)
    hipMemsetAsync(deg, 0, NN * sizeof(int), stream);
    conv_hist<<<(N4 + TB - 1) / TB, TB, 0, stream>>>(
        (const float4*)x, (ushort4*)xh, (const int4*)dstI, deg, (int4*)eoff);

    block_scan<<<NB, 256, 0, stream>>>(deg, iscan, bsum,
        P[3], P[5], P[11], P[13], P[19], W1t, W2t, W3t, W21t, W12t);
    scan_bsum<<<1, 256, 0, stream>>>(bsum, boff);
    finalize_bounds<<<NB, 256, 0, stream>>>(deg, iscan, boff, rowptr, batch, gstart);
    fill_csr2<<<(NQ + TB - 1) / TB, TB, 0, stream>>>(
        (const int4*)srcI, (const int4*)dstI, rowptr, (const int4*)eoff, esrc);

    const int GB   = (NN + 3) / 4;     // gathers: 1 wave/node
    const int FB64 = (NN + 63) / 64;
    const int FB32 = (NN + 31) / 32;

    gather_L0<<<GB, 256, 0, stream>>>(xh, esrc, rowptr, aggh);
    gemm_L0<<<FB64, 256, 0, stream>>>(aggh, z1h, W1t, W2t, W3t,
        P[4], P[6], P[7], P[8], P[9], P[10]);
    gather_L1<<<GB, 256, 0, stream>>>(z1h, esrc, rowptr, P[12], agg1h);
    gemm_L1<<<FB64, 256, 0, stream>>>(agg1h, z2h, W21t, W12t,
        P[14], P[15], P[16], P[17], P[18]);
    gather_L2<<<GB, 256, 0, stream>>>(z2h, esrc, rowptr, P[20], agg2h);
    gemm_L2<<<FB32, 256, 0, stream>>>(agg2h, logits,
        P[21], P[22], P[23], P[24], P[25], P[26], Wlin, blin);

    seg_softmax<<<NG, 256, 0, stream>>>(logits, gstart, outp);
}